// Round 6
// baseline (374.787 us; speedup 1.0000x reference)
//
#include <hip/hip_runtime.h>
#include <stdint.h>

#define KTOT 4507
#define POSTN 1000
#define ATOT 159882
#define NIMG 4
#define CAND_CAP 4096
#define SLOTCAP 5000  // per-image compact capacity (koff spacing = lvl*1000)
#define CHUNK 256     // rows per staged scan chunk
#define BPI 22        // hist/gather blocks per image: 15+4+1+1+1

// ---------- helpers ----------

__device__ inline unsigned fmono(float f) {
    unsigned u = __float_as_uint(f);
    return (u & 0x80000000u) ? ~u : (u | 0x80000000u);
}
__device__ inline float fmono_inv(unsigned u) {
    unsigned b = (u & 0x80000000u) ? (u ^ 0x80000000u) : ~u;
    return __uint_as_float(b);
}

// exclusive prefix over a 1024-thread block; warpSums = LDS int[>=16]; call uniformly.
__device__ inline int blockExclScan(int v, int* warpSums) {
    int tid = threadIdx.x;
    int lane = tid & 63, wid = tid >> 6;
    int x = v;
#pragma unroll
    for (int d = 1; d < 64; d <<= 1) {
        int y = __shfl_up(x, d);
        if (lane >= d) x += y;
    }
    if (lane == 63) warpSums[wid] = x;
    __syncthreads();
    if (wid == 0) {
        int s = (lane < 16) ? warpSums[lane] : 0;
#pragma unroll
        for (int d = 1; d < 16; d <<= 1) {
            int y = __shfl_up(s, d);
            if (lane >= d) s += y;
        }
        if (lane < 16) warpSums[lane] = s;
    }
    __syncthreads();
    int wpre = (wid == 0) ? 0 : warpSums[wid - 1];
    return wpre + (x - v);
}

__device__ __constant__ int c_lvlOff[5] = {0, 120000, 150000, 157500, 159375};
__device__ __constant__ int c_lvlN[5]   = {120000, 30000, 7500, 1875, 507};
__device__ __constant__ int c_slsz[5]   = {8000, 7500, 7500, 1875, 507};
__device__ __constant__ int c_blvl[BPI] = {0,0,0,0,0,0,0,0,0,0,0,0,0,0,0, 1,1,1,1, 2, 3, 4};
__device__ __constant__ int c_bsl[BPI]  = {0,1,2,3,4,5,6,7,8,9,10,11,12,13,14, 0,1,2,3, 0, 0, 0};

// ---------- stage A1: sliced histogram -> global per-(img,lvl) 4096-bin hist ----------

__global__ __launch_bounds__(1024) void hist_kernel(const float* __restrict__ obj,
                                                    unsigned* __restrict__ ghist) {
    __shared__ unsigned hist[4096];
    int img = blockIdx.x / BPI, b = blockIdx.x % BPI;
    int lvl = c_blvl[b], sl = c_bsl[b];
    int n = c_lvlN[lvl];
    int s0 = sl * c_slsz[lvl];
    int send = min(s0 + c_slsz[lvl], n);
    const float* src = obj + (size_t)img * ATOT + c_lvlOff[lvl];
    int tid = threadIdx.x;

    for (int i = tid; i < 4096; i += 1024) hist[i] = 0u;
    __syncthreads();

    int base = s0 + tid, last = send - 1;
    float v0 = src[min(base,        last)];
    float v1 = src[min(base + 1024, last)];
    float v2 = src[min(base + 2048, last)];
    float v3 = src[min(base + 3072, last)];
    float v4 = src[min(base + 4096, last)];
    float v5 = src[min(base + 5120, last)];
    float v6 = src[min(base + 6144, last)];
    float v7 = src[min(base + 7168, last)];
#define HIST1(U, VV) if (base + (U)*1024 < send) atomicAdd(&hist[fmono(VV) >> 20], 1u);
    HIST1(0, v0) HIST1(1, v1) HIST1(2, v2) HIST1(3, v3)
    HIST1(4, v4) HIST1(5, v5) HIST1(6, v6) HIST1(7, v7)
#undef HIST1
    __syncthreads();

    unsigned* gh = ghist + (size_t)(img * 5 + lvl) * 4096;
    for (int i = tid; i < 4096; i += 1024) {
        unsigned c = hist[i];
        if (c) atomicAdd(&gh[i], c);
    }
}

// ---------- stage A2: per-slice candidate gather (bins >= bstar) -> global cand buf ----------

__global__ __launch_bounds__(1024) void gather_kernel(const float* __restrict__ obj,
                                                      const unsigned* __restrict__ ghist,
                                                      unsigned long long* __restrict__ gcand,
                                                      int* __restrict__ gcnt) {
    __shared__ int s_misc[32];
    __shared__ int s_bstar;
    int img = blockIdx.x / BPI, b = blockIdx.x % BPI;
    int lvl = c_blvl[b], sl = c_bsl[b];
    int grp = img * 5 + lvl;
    int n = c_lvlN[lvl];
    int k = (lvl == 4) ? 507 : 1000;
    int s0 = sl * c_slsz[lvl];
    int send = min(s0 + c_slsz[lvl], n);
    const float* src = obj + (size_t)img * ATOT + c_lvlOff[lvl];
    int tid = threadIdx.x;
    int lane = tid & 63;

    // prefix over the completed global histogram (uint4 per thread)
    const uint4* gh4 = (const uint4*)(ghist + (size_t)grp * 4096);
    uint4 cc = gh4[tid];
    int mysum = (int)(cc.x + cc.y + cc.z + cc.w);
    int excl = blockExclScan(mysum, s_misc);
    int target = n - k;
    {
        int P = excl;
        if ((int)cc.x > 0 && P <= target && target < P + (int)cc.x) s_bstar = 4 * tid + 0;
        P += (int)cc.x;
        if ((int)cc.y > 0 && P <= target && target < P + (int)cc.y) s_bstar = 4 * tid + 1;
        P += (int)cc.y;
        if ((int)cc.z > 0 && P <= target && target < P + (int)cc.z) s_bstar = 4 * tid + 2;
        P += (int)cc.z;
        if ((int)cc.w > 0 && P <= target && target < P + (int)cc.w) s_bstar = 4 * tid + 3;
    }
    __syncthreads();
    int bstar = s_bstar;

    unsigned long long* gc = gcand + (size_t)grp * CAND_CAP;
    int base = s0 + tid, last = send - 1;
    float v0 = src[min(base,        last)];
    float v1 = src[min(base + 1024, last)];
    float v2 = src[min(base + 2048, last)];
    float v3 = src[min(base + 3072, last)];
    float v4 = src[min(base + 4096, last)];
    float v5 = src[min(base + 5120, last)];
    float v6 = src[min(base + 6144, last)];
    float v7 = src[min(base + 7168, last)];
#define PUSH1(U, VV)                                                                     \
    {                                                                                    \
        int ix = base + (U) * 1024;                                                      \
        unsigned key = fmono(VV);                                                        \
        bool s = (ix < send) && ((int)(key >> 20) >= bstar);                             \
        unsigned long long mk = __ballot(s);                                             \
        if (mk) {                                                                        \
            int pre = __popcll(mk & ((1ULL << lane) - 1ULL));                            \
            int ldr = __builtin_ctzll(mk);                                               \
            int basew = 0;                                                               \
            if (lane == ldr) basew = atomicAdd(&gcnt[grp], __popcll(mk));                \
            basew = __shfl(basew, ldr);                                                  \
            if (s) {                                                                     \
                int pos = basew + pre;                                                   \
                if (pos < CAND_CAP)                                                      \
                    gc[pos] = ((unsigned long long)key << 32) | (unsigned)(~(unsigned)ix); \
            }                                                                            \
        }                                                                                \
    }
    PUSH1(0, v0) PUSH1(1, v1) PUSH1(2, v2) PUSH1(3, v3)
    PUSH1(4, v4) PUSH1(5, v5) PUSH1(6, v6) PUSH1(7, v7)
#undef PUSH1
}

// ---------- stage B: rank candidates + decode + score + valid + compaction (fused) ----------

__global__ __launch_bounds__(1024) void rankdecode_kernel(
    const float* __restrict__ deltas, const float* __restrict__ anchors,
    const unsigned long long* __restrict__ gcand, const int* __restrict__ gcnt,
    float* __restrict__ sx1, float* __restrict__ sy1, float* __restrict__ sx2,
    float* __restrict__ sy2, float* __restrict__ sscore,
    float* __restrict__ cx1, float* __restrict__ cy1, float* __restrict__ cx2,
    float* __restrict__ cy2, float* __restrict__ car,
    unsigned long long* __restrict__ ckey, int* __restrict__ cslot, int* __restrict__ cm) {
    __shared__ unsigned long long ck[CAND_CAP];
    __shared__ int sIdxL[1000];
    __shared__ float sLogL[1000];
    __shared__ int s_warp[32];

    int grp = blockIdx.x;
    int img = grp / 5, lvl = grp % 5;
    int kn = (lvl == 4) ? 507 : 1000;
    int koff = lvl * 1000;
    int tid = threadIdx.x;
    int m = gcnt[grp];
    if (m > CAND_CAP) m = CAND_CAP;

    const unsigned long long* gc = gcand + (size_t)grp * CAND_CAP;
    for (int i = tid; i < CAND_CAP; i += 1024) ck[i] = (i < m) ? gc[i] : 0ULL;
    __syncthreads();

    // rank = #{keys > mine} over candidate set (keys distinct -> bijection).
    // Broadcast LDS reads (all lanes same j) are conflict-free.
    {
        int c0 = tid, c1 = tid + 1024, c2 = tid + 2048, c3 = tid + 3072;
        int mm1 = m - 1;  // m >= k >= 507 > 0
        unsigned long long k0 = ck[min(c0, mm1)], k1 = ck[min(c1, mm1)];
        unsigned long long k2 = ck[min(c2, mm1)], k3 = ck[min(c3, mm1)];
        int n0 = 0, n1 = 0, n2 = 0, n3 = 0;
#pragma unroll 4
        for (int j = 0; j < m; j++) {
            unsigned long long kj = ck[j];
            n0 += (kj > k0); n1 += (kj > k1); n2 += (kj > k2); n3 += (kj > k3);
        }
#define EMIT(C, N, K)                                                                    \
        if ((C) < m && (N) < kn) {                                                       \
            unsigned hi = (unsigned)((K) >> 32);                                         \
            int li = (int)(~(unsigned)(K));                                              \
            sIdxL[N] = c_lvlOff[lvl] + li;                                               \
            sLogL[N] = fmono_inv(hi);                                                    \
        }
        EMIT(c0, n0, k0) EMIT(c1, n1, k1) EMIT(c2, n2, k2) EMIT(c3, n3, k3)
#undef EMIT
    }
    __syncthreads();

    // decode rank r = tid (identical arithmetic to reference path)
    int r = tid;
    size_t o = (size_t)img * KTOT + koff + r;
    float x1 = 0.f, y1 = 0.f, x2 = 0.f, y2 = 0.f, s = 0.f;
    int valid = 0;
    if (r < kn) {
        int idx = sIdxL[r];
        float logit = sLogL[r];
        float ef = (float)exp(-(double)logit);
        s = 1.0f / __fadd_rn(1.0f, ef);
        float a0 = anchors[(size_t)idx * 4 + 0], a1 = anchors[(size_t)idx * 4 + 1];
        float a2 = anchors[(size_t)idx * 4 + 2], a3 = anchors[(size_t)idx * 4 + 3];
        const float* dp = deltas + ((size_t)img * ATOT + idx) * 4;
        float dx = dp[0], dy = dp[1];
        const float BCLIP = 4.135166556742356f;  // log(1000/16)
        float dw = fminf(dp[2], BCLIP), dh = fminf(dp[3], BCLIP);
        float wa = __fsub_rn(a2, a0), ha = __fsub_rn(a3, a1);
        float cxa = __fadd_rn(a0, __fmul_rn(0.5f, wa));
        float cya = __fadd_rn(a1, __fmul_rn(0.5f, ha));
        float cx = __fadd_rn(__fmul_rn(dx, wa), cxa);
        float cy = __fadd_rn(__fmul_rn(dy, ha), cya);
        float w = __fmul_rn((float)exp((double)dw), wa);
        float h = __fmul_rn((float)exp((double)dh), ha);
        x1 = __fsub_rn(cx, __fmul_rn(0.5f, w));
        y1 = __fsub_rn(cy, __fmul_rn(0.5f, h));
        x2 = __fadd_rn(cx, __fmul_rn(0.5f, w));
        y2 = __fadd_rn(cy, __fmul_rn(0.5f, h));
        x1 = fminf(fmaxf(x1, 0.0f), 800.0f);
        y1 = fminf(fmaxf(y1, 0.0f), 800.0f);
        x2 = fminf(fmaxf(x2, 0.0f), 800.0f);
        y2 = fminf(fmaxf(y2, 0.0f), 800.0f);
        valid = (__fsub_rn(x2, x1) >= 0.001f) && (__fsub_rn(y2, y1) >= 0.001f) && (s >= 0.0f);
        sx1[o] = x1; sy1[o] = y1; sx2[o] = x2; sy2[o] = y2; sscore[o] = s;
    }

    int pos = blockExclScan(valid, s_warp);
    if (valid) {
        float lf = 1000.0f * (float)lvl;
        size_t cb = (size_t)img * SLOTCAP + koff + pos;
        float ox1 = __fadd_rn(x1, lf);
        float oy1 = __fadd_rn(y1, lf);
        float ox2 = __fadd_rn(x2, lf);
        float oy2 = __fadd_rn(y2, lf);
        cx1[cb] = ox1; cy1[cb] = oy1; cx2[cb] = ox2; cy2[cb] = oy2;
        car[cb] = __fmul_rn(__fsub_rn(ox2, ox1), __fsub_rn(oy2, oy1));
        int p = koff + r;
        ckey[cb] = ((unsigned long long)fmono(s) << 32) | (unsigned)(~(unsigned)p);
        cslot[cb] = p;
    }
    if (tid == 1023) cm[grp] = pos + valid;
}

// ---------- stage C: suppression-mask build, one wave per 64x64 tile, ballot form ----------

__global__ __launch_bounds__(512) void mask_kernel(
    const float* __restrict__ cx1, const float* __restrict__ cy1,
    const float* __restrict__ cx2, const float* __restrict__ cy2,
    const float* __restrict__ car, const int* __restrict__ cm,
    unsigned long long* __restrict__ maskBuf) {
    __shared__ float lx1[1000], ly1[1000], lx2[1000], ly2[1000], lar[1000];
    int iq = blockIdx.y;
    int img = iq / 5, lvl = iq % 5;
    int m = cm[img * 5 + lvl];
    int W = (m + 63) >> 6;
    int T = (W * (W + 1)) >> 1;  // one task per lower-triangular 64x64 tile (w, c<=w)
    int tbase = blockIdx.x * 8;
    if (tbase >= T) return;

    size_t cb0 = (size_t)img * SLOTCAP + lvl * 1000;
    for (int q = threadIdx.x; q < m; q += 512) {
        lx1[q] = cx1[cb0 + q]; ly1[q] = cy1[cb0 + q];
        lx2[q] = cx2[cb0 + q]; ly2[q] = cy2[cb0 + q];
        lar[q] = car[cb0 + q];
    }
    __syncthreads();

    int wv = threadIdx.x >> 6, lane = threadIdx.x & 63;
    int t = tbase + wv;
    if (t >= T) return;
    int w = (int)((sqrtf(8.0f * (float)t + 1.0f) - 1.0f) * 0.5f);
    while (((w + 1) * (w + 2)) / 2 <= t) w++;
    while ((w * (w + 1)) / 2 > t) w--;
    int c = t - ((w * (w + 1)) >> 1);

    size_t mOff = (size_t)img * 68056 + (size_t)lvl * 16000;
    int Wa = (lvl == 4) ? 8 : 16;
    unsigned long long* M = maskBuf + mOff;

    int j = (w << 6) + lane;
    bool jv = j < m;
    float jx1 = jv ? lx1[j] : 0.f, jy1 = jv ? ly1[j] : 0.f;
    float jx2 = jv ? lx2[j] : 0.f, jy2 = jv ? ly2[j] : 0.f;
    float jar = jv ? lar[j] : 0.f;

    unsigned long long myword = 0ULL;
    int i0 = c << 6, i1 = min(i0 + 64, m);
    for (int i = i0; i < i1; i++) {
        float ix1 = lx1[i], iy1 = ly1[i], ix2 = lx2[i], iy2 = ly2[i], iar = lar[i];
        float ltx = fmaxf(ix1, jx1);
        float lty = fmaxf(iy1, jy1);
        float rbx = fminf(ix2, jx2);
        float rby = fminf(iy2, jy2);
        float wq = fmaxf(__fsub_rn(rbx, ltx), 0.0f);
        float hq = fmaxf(__fsub_rn(rby, lty), 0.0f);
        float inter = __fmul_rn(wq, hq);
        float uni = __fsub_rn(__fadd_rn(iar, jar), inter);
        float iou = inter / uni;  // keep IEEE div: decisions must match reference exactly
        bool bit = jv && (j > i) && (iou > 0.7f);
        unsigned long long bal = __ballot(bit);
        if (lane == (i & 63)) myword = bal;
    }
    int irow = i0 + lane;
    if (irow < i1) M[(size_t)irow * Wa + w] = myword;
}

// ---------- stage C2: greedy scan, LDS-staged (wave 0 scans, waves 1-3 prefetch) ----------

__global__ __launch_bounds__(256, 1) void scan_kernel(
    const unsigned long long* __restrict__ maskBuf, const int* __restrict__ cm,
    unsigned long long* __restrict__ keepWords) {
    __shared__ unsigned long long sbuf[2][CHUNK * 16];  // 64 KB double buffer
    int img = blockIdx.x / 5, lvl = blockIdx.x % 5;
    int m = cm[img * 5 + lvl];
    int W = (m + 63) >> 6;
    int Wa = (lvl == 4) ? 8 : 16;
    const unsigned long long* M = maskBuf + (size_t)img * 68056 + (size_t)lvl * 16000;
    int tid = threadIdx.x;
    int wv = tid >> 6, lane = tid & 63;
    int nch = (m + CHUNK - 1) / CHUNK;

    {
        int words0 = min(CHUNK, m) * Wa;
        for (int u = tid; u < words0; u += 256) sbuf[0][u] = M[u];
    }
    __syncthreads();

    unsigned long long remv = 0ULL;
    unsigned long long kw = 0ULL;

    for (int ch = 0; ch < nch; ch++) {
        if (wv > 0 && ch + 1 < nch) {
            int rbase = (ch + 1) * CHUNK;
            int wordsN = (min(rbase + CHUNK, m) - rbase) * Wa;
            const unsigned long long* srcp = M + (size_t)rbase * Wa;
            unsigned long long* dstp = sbuf[(ch + 1) & 1];
            for (int u = tid - 64; u < wordsN; u += 192) dstp[u] = srcp[u];
        }
        if (wv == 0) {
            const unsigned long long* buf = sbuf[ch & 1];
            int i0 = ch * CHUNK, i1 = min(i0 + CHUNK, m);
            bool own = lane < W;
#define LD(ROW) ((own && (ROW) < i1) ? buf[((ROW) - i0) * Wa + lane] : 0ULL)
            unsigned long long p0 = LD(i0 + 0), p1 = LD(i0 + 1), p2 = LD(i0 + 2),
                               p3 = LD(i0 + 3), p4 = LD(i0 + 4), p5 = LD(i0 + 5),
                               p6 = LD(i0 + 6), p7 = LD(i0 + 7);
#define STEP(Q, IDX)                                                                     \
            {                                                                            \
                int i_ = (IDX);                                                          \
                if (i_ < i1) {                                                           \
                    bool mine = ((remv >> (i_ & 63)) & 1ULL) != 0ULL;                    \
                    unsigned long long bal = __ballot(mine);                             \
                    bool alive = ((bal >> (i_ >> 6)) & 1ULL) == 0ULL;                    \
                    if (alive) remv |= (Q);                                              \
                    if ((i_ >> 6) == lane) kw |= (unsigned long long)alive << (i_ & 63); \
                }                                                                        \
                (Q) = LD(i_ + 8);                                                        \
            }
            for (int i = i0; i < i1; i += 8) {
                STEP(p0, i + 0) STEP(p1, i + 1) STEP(p2, i + 2) STEP(p3, i + 3)
                STEP(p4, i + 4) STEP(p5, i + 5) STEP(p6, i + 6) STEP(p7, i + 7)
            }
#undef STEP
#undef LD
        }
        __syncthreads();
    }
    if (wv == 0 && lane < 16) keepWords[(img * 5 + lvl) * 16 + lane] = kw;
}

// ---------- stage D: compaction + global rank + output ----------

__global__ __launch_bounds__(1024) void scanout_kernel(
    const float* __restrict__ sx1, const float* __restrict__ sy1,
    const float* __restrict__ sx2, const float* __restrict__ sy2,
    const float* __restrict__ sscore,
    const unsigned long long* __restrict__ ckey, const int* __restrict__ cslot,
    const int* __restrict__ cm, const unsigned long long* __restrict__ keepWords,
    float* __restrict__ out) {
    __shared__ unsigned long long kkey[SLOTCAP];
    __shared__ int kslot[SLOTCAP];
    __shared__ int s_warp[32];
    __shared__ int s_cnt[5];

    int img = blockIdx.x, tid = threadIdx.x;

    for (int lvl = 0; lvl < 5; lvl++) {
        int m = cm[img * 5 + lvl];
        int koff = lvl * 1000;
        int flag = 0;
        if (tid < m)
            flag = (int)((keepWords[(img * 5 + lvl) * 16 + (tid >> 6)] >> (tid & 63)) & 1ULL);
        int pos = blockExclScan(flag, s_warp);
        if (flag) {
            size_t cb = (size_t)img * SLOTCAP + koff + tid;
            kkey[koff + pos] = ckey[cb];
            kslot[koff + pos] = cslot[cb];
        }
        if (tid == 1023) s_cnt[lvl] = pos + flag;
        __syncthreads();
    }

    int tK = s_cnt[0] + s_cnt[1] + s_cnt[2] + s_cnt[3] + s_cnt[4];

    for (int lvl = 0; lvl < 5; lvl++) {
        int Kc = s_cnt[lvl];
        int koff = lvl * 1000;
        for (int q = tid; q < Kc; q += 1024) {
            unsigned long long key = kkey[koff + q];
            int rank = q;
#pragma unroll
            for (int ol = 0; ol < 5; ol++) {
                if (ol == lvl) continue;
                int lo = 0, hi = s_cnt[ol], base = ol * 1000;
                while (lo < hi) {
                    int mid = (lo + hi) >> 1;
                    if (kkey[base + mid] > key) lo = mid + 1; else hi = mid;
                }
                rank += lo;
            }
            if (rank < POSTN) {
                int slot = kslot[koff + q];
                size_t o = (size_t)img * KTOT + slot;
                float* dst = out + ((size_t)img * POSTN + rank) * 5;
                dst[0] = sx1[o]; dst[1] = sy1[o]; dst[2] = sx2[o]; dst[3] = sy2[o];
                dst[4] = sscore[o];
            }
        }
    }

    int z0 = tK < POSTN ? tK : POSTN;
    int nz = (POSTN - z0) * 5;
    float* ob = out + (size_t)img * POSTN * 5 + (size_t)z0 * 5;
    for (int u = tid; u < nz; u += 1024) ob[u] = 0.f;
}

// ---------- host ----------

extern "C" void kernel_launch(void* const* d_in, const int* in_sizes, int n_in,
                              void* d_out, int out_size, void* d_ws, size_t ws_size,
                              hipStream_t stream) {
    const float* obj = (const float*)d_in[0];
    const float* deltas = (const float*)d_in[1];
    const float* anchors = (const float*)d_in[2];
    float* out = (float*)d_out;

    char* ws = (char*)d_ws;
    size_t off = 0;
    auto alloc = [&](size_t bytes) {
        size_t o = off;
        off += (bytes + 255) & ~(size_t)255;
        return o;
    };
    unsigned* ghist = (unsigned*)(ws + alloc((size_t)NIMG * 5 * 4096 * 4));
    int* gcnt = (int*)(ws + alloc((size_t)NIMG * 5 * 4));
    unsigned long long* gcand = (unsigned long long*)(ws + alloc((size_t)NIMG * 5 * CAND_CAP * 8));
    float* sx1 = (float*)(ws + alloc((size_t)NIMG * KTOT * 4));
    float* sy1 = (float*)(ws + alloc((size_t)NIMG * KTOT * 4));
    float* sx2 = (float*)(ws + alloc((size_t)NIMG * KTOT * 4));
    float* sy2 = (float*)(ws + alloc((size_t)NIMG * KTOT * 4));
    float* sscore = (float*)(ws + alloc((size_t)NIMG * KTOT * 4));
    float* cx1 = (float*)(ws + alloc((size_t)NIMG * SLOTCAP * 4));
    float* cy1 = (float*)(ws + alloc((size_t)NIMG * SLOTCAP * 4));
    float* cx2 = (float*)(ws + alloc((size_t)NIMG * SLOTCAP * 4));
    float* cy2 = (float*)(ws + alloc((size_t)NIMG * SLOTCAP * 4));
    float* car = (float*)(ws + alloc((size_t)NIMG * SLOTCAP * 4));
    unsigned long long* ckey = (unsigned long long*)(ws + alloc((size_t)NIMG * SLOTCAP * 8));
    int* cslot = (int*)(ws + alloc((size_t)NIMG * SLOTCAP * 4));
    int* cm = (int*)(ws + alloc((size_t)NIMG * 5 * 4));
    unsigned long long* maskBuf = (unsigned long long*)(ws + alloc((size_t)NIMG * 68056ULL * 8));
    unsigned long long* keepWords = (unsigned long long*)(ws + alloc((size_t)NIMG * 5 * 16 * 8));

    hipMemsetAsync(ghist, 0, (size_t)NIMG * 5 * 4096 * 4, stream);
    hipMemsetAsync(gcnt, 0, (size_t)NIMG * 5 * 4, stream);

    hist_kernel<<<dim3(NIMG * BPI), dim3(1024), 0, stream>>>(obj, ghist);
    gather_kernel<<<dim3(NIMG * BPI), dim3(1024), 0, stream>>>(obj, ghist, gcand, gcnt);
    rankdecode_kernel<<<dim3(NIMG * 5), dim3(1024), 0, stream>>>(
        deltas, anchors, gcand, gcnt, sx1, sy1, sx2, sy2, sscore,
        cx1, cy1, cx2, cy2, car, ckey, cslot, cm);
    mask_kernel<<<dim3(17, NIMG * 5), dim3(512), 0, stream>>>(cx1, cy1, cx2, cy2, car, cm,
                                                              maskBuf);
    scan_kernel<<<dim3(NIMG * 5), dim3(256), 0, stream>>>(maskBuf, cm, keepWords);
    scanout_kernel<<<dim3(NIMG), dim3(1024), 0, stream>>>(
        sx1, sy1, sx2, sy2, sscore, ckey, cslot, cm, keepWords, out);
}

// Round 7
// 241.127 us; speedup vs baseline: 1.5543x; 1.5543x over previous
//
#include <hip/hip_runtime.h>
#include <stdint.h>

#define KTOT 4507
#define POSTN 1000
#define ATOT 159882
#define NIMG 4
#define CAND_CAP 4096
#define SLOTCAP 5000  // per-image compact capacity (koff spacing = lvl*1000)
#define CHUNK 256     // rows per staged scan chunk
#define BPI 22        // hist/gather blocks per image: 15+4+1+1+1

// ---------- helpers ----------

__device__ inline unsigned fmono(float f) {
    unsigned u = __float_as_uint(f);
    return (u & 0x80000000u) ? ~u : (u | 0x80000000u);
}
__device__ inline float fmono_inv(unsigned u) {
    unsigned b = (u & 0x80000000u) ? (u ^ 0x80000000u) : ~u;
    return __uint_as_float(b);
}

// exclusive prefix over a 1024-thread block; warpSums = LDS int[>=16]; call uniformly.
__device__ inline int blockExclScan(int v, int* warpSums) {
    int tid = threadIdx.x;
    int lane = tid & 63, wid = tid >> 6;
    int x = v;
#pragma unroll
    for (int d = 1; d < 64; d <<= 1) {
        int y = __shfl_up(x, d);
        if (lane >= d) x += y;
    }
    if (lane == 63) warpSums[wid] = x;
    __syncthreads();
    if (wid == 0) {
        int s = (lane < 16) ? warpSums[lane] : 0;
#pragma unroll
        for (int d = 1; d < 16; d <<= 1) {
            int y = __shfl_up(s, d);
            if (lane >= d) s += y;
        }
        if (lane < 16) warpSums[lane] = s;
    }
    __syncthreads();
    int wpre = (wid == 0) ? 0 : warpSums[wid - 1];
    return wpre + (x - v);
}

__device__ __constant__ int c_lvlOff[5] = {0, 120000, 150000, 157500, 159375};
__device__ __constant__ int c_lvlN[5]   = {120000, 30000, 7500, 1875, 507};
__device__ __constant__ int c_slsz[5]   = {8000, 7500, 7500, 1875, 507};
__device__ __constant__ int c_blvl[BPI] = {0,0,0,0,0,0,0,0,0,0,0,0,0,0,0, 1,1,1,1, 2, 3, 4};
__device__ __constant__ int c_bsl[BPI]  = {0,1,2,3,4,5,6,7,8,9,10,11,12,13,14, 0,1,2,3, 0, 0, 0};
__device__ __constant__ int c_bstart[5] = {0, 15, 19, 20, 21};
__device__ __constant__ int c_bcnt[5]   = {15, 4, 1, 1, 1};

// ---------- stage A1: sliced histogram -> global per-(img,lvl) 4096-bin hist ----------

__global__ __launch_bounds__(1024) void hist_kernel(const float* __restrict__ obj,
                                                    unsigned* __restrict__ ghist) {
    __shared__ unsigned hist[4096];
    int img = blockIdx.x / BPI, b = blockIdx.x % BPI;
    int lvl = c_blvl[b], sl = c_bsl[b];
    int n = c_lvlN[lvl];
    int s0 = sl * c_slsz[lvl];
    int send = min(s0 + c_slsz[lvl], n);
    const float* src = obj + (size_t)img * ATOT + c_lvlOff[lvl];
    int tid = threadIdx.x;

    for (int i = tid; i < 4096; i += 1024) hist[i] = 0u;
    __syncthreads();

    int base = s0 + tid, last = send - 1;
    float v0 = src[min(base,        last)];
    float v1 = src[min(base + 1024, last)];
    float v2 = src[min(base + 2048, last)];
    float v3 = src[min(base + 3072, last)];
    float v4 = src[min(base + 4096, last)];
    float v5 = src[min(base + 5120, last)];
    float v6 = src[min(base + 6144, last)];
    float v7 = src[min(base + 7168, last)];
#define HIST1(U, VV) if (base + (U)*1024 < send) atomicAdd(&hist[fmono(VV) >> 20], 1u);
    HIST1(0, v0) HIST1(1, v1) HIST1(2, v2) HIST1(3, v3)
    HIST1(4, v4) HIST1(5, v5) HIST1(6, v6) HIST1(7, v7)
#undef HIST1
    __syncthreads();

    unsigned* gh = ghist + (size_t)(img * 5 + lvl) * 4096;
    for (int i = tid; i < 4096; i += 1024) {
        unsigned c = hist[i];
        if (c) atomicAdd(&gh[i], c);
    }
}

// ---------- stage A2: per-slice gather into PRIVATE segment (LDS counter only) ----------

__global__ __launch_bounds__(1024) void gather_kernel(const float* __restrict__ obj,
                                                      const unsigned* __restrict__ ghist,
                                                      unsigned long long* __restrict__ gcand,
                                                      int* __restrict__ gcnt) {
    __shared__ int s_misc[32];
    __shared__ int s_bstar, s_cnt;
    int img = blockIdx.x / BPI, b = blockIdx.x % BPI;
    int lvl = c_blvl[b], sl = c_bsl[b];
    int grp = img * 5 + lvl;
    int seg = img * BPI + b;
    int n = c_lvlN[lvl];
    int k = (lvl == 4) ? 507 : 1000;
    int s0 = sl * c_slsz[lvl];
    int send = min(s0 + c_slsz[lvl], n);
    const float* src = obj + (size_t)img * ATOT + c_lvlOff[lvl];
    int tid = threadIdx.x;
    int lane = tid & 63;

    if (tid == 0) s_cnt = 0;

    // bstar from the completed global histogram (uint4 per thread)
    const uint4* gh4 = (const uint4*)(ghist + (size_t)grp * 4096);
    uint4 cc = gh4[tid];
    int mysum = (int)(cc.x + cc.y + cc.z + cc.w);
    int excl = blockExclScan(mysum, s_misc);
    int target = n - k;
    {
        int P = excl;
        if ((int)cc.x > 0 && P <= target && target < P + (int)cc.x) s_bstar = 4 * tid + 0;
        P += (int)cc.x;
        if ((int)cc.y > 0 && P <= target && target < P + (int)cc.y) s_bstar = 4 * tid + 1;
        P += (int)cc.y;
        if ((int)cc.z > 0 && P <= target && target < P + (int)cc.z) s_bstar = 4 * tid + 2;
        P += (int)cc.z;
        if ((int)cc.w > 0 && P <= target && target < P + (int)cc.w) s_bstar = 4 * tid + 3;
    }
    __syncthreads();
    int bstar = s_bstar;

    unsigned long long* gc = gcand + (size_t)seg * CAND_CAP;
    int base = s0 + tid, last = send - 1;
    float v0 = src[min(base,        last)];
    float v1 = src[min(base + 1024, last)];
    float v2 = src[min(base + 2048, last)];
    float v3 = src[min(base + 3072, last)];
    float v4 = src[min(base + 4096, last)];
    float v5 = src[min(base + 5120, last)];
    float v6 = src[min(base + 6144, last)];
    float v7 = src[min(base + 7168, last)];
#define PUSH1(U, VV)                                                                     \
    {                                                                                    \
        int ix = base + (U) * 1024;                                                      \
        unsigned key = fmono(VV);                                                        \
        bool s = (ix < send) && ((int)(key >> 20) >= bstar);                             \
        unsigned long long mk = __ballot(s);                                             \
        if (mk) {                                                                        \
            int pre = __popcll(mk & ((1ULL << lane) - 1ULL));                            \
            int ldr = __builtin_ctzll(mk);                                               \
            int basew = 0;                                                               \
            if (lane == ldr) basew = atomicAdd(&s_cnt, __popcll(mk));                    \
            basew = __shfl(basew, ldr);                                                  \
            if (s) {                                                                     \
                int pos = basew + pre;                                                   \
                if (pos < CAND_CAP)                                                      \
                    gc[pos] = ((unsigned long long)key << 32) | (unsigned)(~(unsigned)ix); \
            }                                                                            \
        }                                                                                \
    }
    PUSH1(0, v0) PUSH1(1, v1) PUSH1(2, v2) PUSH1(3, v3)
    PUSH1(4, v4) PUSH1(5, v5) PUSH1(6, v6) PUSH1(7, v7)
#undef PUSH1
    __syncthreads();
    if (tid == 0) gcnt[seg] = min(s_cnt, CAND_CAP);
}

// ---------- stage B: concat segments + bitonic sort + decode + compaction (fused) ----------

__global__ __launch_bounds__(1024) void rankdecode_kernel(
    const float* __restrict__ deltas, const float* __restrict__ anchors,
    const unsigned long long* __restrict__ gcand, const int* __restrict__ gcnt,
    float* __restrict__ sx1, float* __restrict__ sy1, float* __restrict__ sx2,
    float* __restrict__ sy2, float* __restrict__ sscore,
    float* __restrict__ cx1, float* __restrict__ cy1, float* __restrict__ cx2,
    float* __restrict__ cy2, float* __restrict__ car,
    unsigned long long* __restrict__ ckey, int* __restrict__ cslot, int* __restrict__ cm) {
    __shared__ unsigned long long ck[CAND_CAP];
    __shared__ int s_warp[32];

    int grp = blockIdx.x;
    int img = grp / 5, lvl = grp % 5;
    int kn = (lvl == 4) ? 507 : 1000;
    int koff = lvl * 1000;
    int tid = threadIdx.x;

    // concat per-slice segments into LDS
    int bs = c_bstart[lvl], bc = c_bcnt[lvl];
    int pref = 0;
    for (int s = 0; s < bc; s++) {
        int c = gcnt[img * BPI + bs + s];
        const unsigned long long* segp = gcand + (size_t)(img * BPI + bs + s) * CAND_CAP;
        for (int i = tid; i < c; i += 1024) {
            int d = pref + i;
            if (d < CAND_CAP) ck[d] = segp[i];
        }
        pref += c;
    }
    int m = min(pref, CAND_CAP);
    int P = 512;
    while (P < m) P <<= 1;  // pow2 sort size, >= kn always (m >= k)
    for (int i = m + tid; i < P; i += 1024) ck[i] = 0ULL;
    __syncthreads();

    // bitonic ascending sort of P u64 keys
    for (unsigned kk = 2; kk <= (unsigned)P; kk <<= 1) {
        for (unsigned j = kk >> 1; j > 0; j >>= 1) {
            for (unsigned i = (unsigned)tid; i < (unsigned)P; i += 1024) {
                unsigned ixj = i ^ j;
                if (ixj > i) {
                    unsigned long long a = ck[i], b = ck[ixj];
                    bool up = ((i & kk) == 0);
                    if ((a > b) == up) { ck[i] = b; ck[ixj] = a; }
                }
            }
            __syncthreads();
        }
    }

    // thread tid holds rank-tid key; decode (identical arithmetic to reference path)
    int r = tid;
    size_t o = (size_t)img * KTOT + koff + r;
    float x1 = 0.f, y1 = 0.f, x2 = 0.f, y2 = 0.f, s = 0.f;
    int valid = 0;
    if (r < kn) {
        unsigned long long key = ck[P - 1 - r];
        int idx = c_lvlOff[lvl] + (int)(~(unsigned)key);
        float logit = fmono_inv((unsigned)(key >> 32));
        float ef = (float)exp(-(double)logit);
        s = 1.0f / __fadd_rn(1.0f, ef);
        float a0 = anchors[(size_t)idx * 4 + 0], a1 = anchors[(size_t)idx * 4 + 1];
        float a2 = anchors[(size_t)idx * 4 + 2], a3 = anchors[(size_t)idx * 4 + 3];
        const float* dp = deltas + ((size_t)img * ATOT + idx) * 4;
        float dx = dp[0], dy = dp[1];
        const float BCLIP = 4.135166556742356f;  // log(1000/16)
        float dw = fminf(dp[2], BCLIP), dh = fminf(dp[3], BCLIP);
        float wa = __fsub_rn(a2, a0), ha = __fsub_rn(a3, a1);
        float cxa = __fadd_rn(a0, __fmul_rn(0.5f, wa));
        float cya = __fadd_rn(a1, __fmul_rn(0.5f, ha));
        float cx = __fadd_rn(__fmul_rn(dx, wa), cxa);
        float cy = __fadd_rn(__fmul_rn(dy, ha), cya);
        float w = __fmul_rn((float)exp((double)dw), wa);
        float h = __fmul_rn((float)exp((double)dh), ha);
        x1 = __fsub_rn(cx, __fmul_rn(0.5f, w));
        y1 = __fsub_rn(cy, __fmul_rn(0.5f, h));
        x2 = __fadd_rn(cx, __fmul_rn(0.5f, w));
        y2 = __fadd_rn(cy, __fmul_rn(0.5f, h));
        x1 = fminf(fmaxf(x1, 0.0f), 800.0f);
        y1 = fminf(fmaxf(y1, 0.0f), 800.0f);
        x2 = fminf(fmaxf(x2, 0.0f), 800.0f);
        y2 = fminf(fmaxf(y2, 0.0f), 800.0f);
        valid = (__fsub_rn(x2, x1) >= 0.001f) && (__fsub_rn(y2, y1) >= 0.001f) && (s >= 0.0f);
        sx1[o] = x1; sy1[o] = y1; sx2[o] = x2; sy2[o] = y2; sscore[o] = s;
    }

    int pos = blockExclScan(valid, s_warp);
    if (valid) {
        float lf = 1000.0f * (float)lvl;
        size_t cb = (size_t)img * SLOTCAP + koff + pos;
        float ox1 = __fadd_rn(x1, lf);
        float oy1 = __fadd_rn(y1, lf);
        float ox2 = __fadd_rn(x2, lf);
        float oy2 = __fadd_rn(y2, lf);
        cx1[cb] = ox1; cy1[cb] = oy1; cx2[cb] = ox2; cy2[cb] = oy2;
        car[cb] = __fmul_rn(__fsub_rn(ox2, ox1), __fsub_rn(oy2, oy1));
        int p = koff + r;
        ckey[cb] = ((unsigned long long)fmono(s) << 32) | (unsigned)(~(unsigned)p);
        cslot[cb] = p;
    }
    if (tid == 1023) cm[grp] = pos + valid;
}

// ---------- stage C: suppression-mask build, one wave per 64x64 tile, ballot form ----------

__global__ __launch_bounds__(512) void mask_kernel(
    const float* __restrict__ cx1, const float* __restrict__ cy1,
    const float* __restrict__ cx2, const float* __restrict__ cy2,
    const float* __restrict__ car, const int* __restrict__ cm,
    unsigned long long* __restrict__ maskBuf) {
    __shared__ float lx1[1000], ly1[1000], lx2[1000], ly2[1000], lar[1000];
    int iq = blockIdx.y;
    int img = iq / 5, lvl = iq % 5;
    int m = cm[img * 5 + lvl];
    int W = (m + 63) >> 6;
    int T = (W * (W + 1)) >> 1;  // one task per lower-triangular 64x64 tile (w, c<=w)
    int tbase = blockIdx.x * 8;
    if (tbase >= T) return;

    size_t cb0 = (size_t)img * SLOTCAP + lvl * 1000;
    for (int q = threadIdx.x; q < m; q += 512) {
        lx1[q] = cx1[cb0 + q]; ly1[q] = cy1[cb0 + q];
        lx2[q] = cx2[cb0 + q]; ly2[q] = cy2[cb0 + q];
        lar[q] = car[cb0 + q];
    }
    __syncthreads();

    int wv = threadIdx.x >> 6, lane = threadIdx.x & 63;
    int t = tbase + wv;
    if (t >= T) return;
    int w = (int)((sqrtf(8.0f * (float)t + 1.0f) - 1.0f) * 0.5f);
    while (((w + 1) * (w + 2)) / 2 <= t) w++;
    while ((w * (w + 1)) / 2 > t) w--;
    int c = t - ((w * (w + 1)) >> 1);

    size_t mOff = (size_t)img * 68056 + (size_t)lvl * 16000;
    int Wa = (lvl == 4) ? 8 : 16;
    unsigned long long* M = maskBuf + mOff;

    int j = (w << 6) + lane;
    bool jv = j < m;
    float jx1 = jv ? lx1[j] : 0.f, jy1 = jv ? ly1[j] : 0.f;
    float jx2 = jv ? lx2[j] : 0.f, jy2 = jv ? ly2[j] : 0.f;
    float jar = jv ? lar[j] : 0.f;

    unsigned long long myword = 0ULL;
    int i0 = c << 6, i1 = min(i0 + 64, m);
    for (int i = i0; i < i1; i++) {
        float ix1 = lx1[i], iy1 = ly1[i], ix2 = lx2[i], iy2 = ly2[i], iar = lar[i];
        float ltx = fmaxf(ix1, jx1);
        float lty = fmaxf(iy1, jy1);
        float rbx = fminf(ix2, jx2);
        float rby = fminf(iy2, jy2);
        float wq = fmaxf(__fsub_rn(rbx, ltx), 0.0f);
        float hq = fmaxf(__fsub_rn(rby, lty), 0.0f);
        float inter = __fmul_rn(wq, hq);
        float uni = __fsub_rn(__fadd_rn(iar, jar), inter);
        float iou = inter / uni;  // keep IEEE div: decisions must match reference exactly
        bool bit = jv && (j > i) && (iou > 0.7f);
        unsigned long long bal = __ballot(bit);
        if (lane == (i & 63)) myword = bal;
    }
    int irow = i0 + lane;
    if (irow < i1) M[(size_t)irow * Wa + w] = myword;
}

// ---------- stage C2: greedy scan, LDS-staged (wave 0 scans, waves 1-3 prefetch) ----------

__global__ __launch_bounds__(256, 1) void scan_kernel(
    const unsigned long long* __restrict__ maskBuf, const int* __restrict__ cm,
    unsigned long long* __restrict__ keepWords) {
    __shared__ unsigned long long sbuf[2][CHUNK * 16];  // 64 KB double buffer
    int img = blockIdx.x / 5, lvl = blockIdx.x % 5;
    int m = cm[img * 5 + lvl];
    int W = (m + 63) >> 6;
    int Wa = (lvl == 4) ? 8 : 16;
    const unsigned long long* M = maskBuf + (size_t)img * 68056 + (size_t)lvl * 16000;
    int tid = threadIdx.x;
    int wv = tid >> 6, lane = tid & 63;
    int nch = (m + CHUNK - 1) / CHUNK;

    {
        int words0 = min(CHUNK, m) * Wa;
        for (int u = tid; u < words0; u += 256) sbuf[0][u] = M[u];
    }
    __syncthreads();

    unsigned long long remv = 0ULL;
    unsigned long long kw = 0ULL;

    for (int ch = 0; ch < nch; ch++) {
        if (wv > 0 && ch + 1 < nch) {
            int rbase = (ch + 1) * CHUNK;
            int wordsN = (min(rbase + CHUNK, m) - rbase) * Wa;
            const unsigned long long* srcp = M + (size_t)rbase * Wa;
            unsigned long long* dstp = sbuf[(ch + 1) & 1];
            for (int u = tid - 64; u < wordsN; u += 192) dstp[u] = srcp[u];
        }
        if (wv == 0) {
            const unsigned long long* buf = sbuf[ch & 1];
            int i0 = ch * CHUNK, i1 = min(i0 + CHUNK, m);
            bool own = lane < W;
#define LD(ROW) ((own && (ROW) < i1) ? buf[((ROW) - i0) * Wa + lane] : 0ULL)
            unsigned long long p0 = LD(i0 + 0), p1 = LD(i0 + 1), p2 = LD(i0 + 2),
                               p3 = LD(i0 + 3), p4 = LD(i0 + 4), p5 = LD(i0 + 5),
                               p6 = LD(i0 + 6), p7 = LD(i0 + 7);
#define STEP(Q, IDX)                                                                     \
            {                                                                            \
                int i_ = (IDX);                                                          \
                if (i_ < i1) {                                                           \
                    bool mine = ((remv >> (i_ & 63)) & 1ULL) != 0ULL;                    \
                    unsigned long long bal = __ballot(mine);                             \
                    bool alive = ((bal >> (i_ >> 6)) & 1ULL) == 0ULL;                    \
                    if (alive) remv |= (Q);                                              \
                    if ((i_ >> 6) == lane) kw |= (unsigned long long)alive << (i_ & 63); \
                }                                                                        \
                (Q) = LD(i_ + 8);                                                        \
            }
            for (int i = i0; i < i1; i += 8) {
                STEP(p0, i + 0) STEP(p1, i + 1) STEP(p2, i + 2) STEP(p3, i + 3)
                STEP(p4, i + 4) STEP(p5, i + 5) STEP(p6, i + 6) STEP(p7, i + 7)
            }
#undef STEP
#undef LD
        }
        __syncthreads();
    }
    if (wv == 0 && lane < 16) keepWords[(img * 5 + lvl) * 16 + lane] = kw;
}

// ---------- stage D: compaction + global rank + output ----------

__global__ __launch_bounds__(1024) void scanout_kernel(
    const float* __restrict__ sx1, const float* __restrict__ sy1,
    const float* __restrict__ sx2, const float* __restrict__ sy2,
    const float* __restrict__ sscore,
    const unsigned long long* __restrict__ ckey, const int* __restrict__ cslot,
    const int* __restrict__ cm, const unsigned long long* __restrict__ keepWords,
    float* __restrict__ out) {
    __shared__ unsigned long long kkey[SLOTCAP];
    __shared__ int kslot[SLOTCAP];
    __shared__ int s_warp[32];
    __shared__ int s_cnt[5];

    int img = blockIdx.x, tid = threadIdx.x;

    for (int lvl = 0; lvl < 5; lvl++) {
        int m = cm[img * 5 + lvl];
        int koff = lvl * 1000;
        int flag = 0;
        if (tid < m)
            flag = (int)((keepWords[(img * 5 + lvl) * 16 + (tid >> 6)] >> (tid & 63)) & 1ULL);
        int pos = blockExclScan(flag, s_warp);
        if (flag) {
            size_t cb = (size_t)img * SLOTCAP + koff + tid;
            kkey[koff + pos] = ckey[cb];
            kslot[koff + pos] = cslot[cb];
        }
        if (tid == 1023) s_cnt[lvl] = pos + flag;
        __syncthreads();
    }

    int tK = s_cnt[0] + s_cnt[1] + s_cnt[2] + s_cnt[3] + s_cnt[4];

    for (int lvl = 0; lvl < 5; lvl++) {
        int Kc = s_cnt[lvl];
        int koff = lvl * 1000;
        for (int q = tid; q < Kc; q += 1024) {
            unsigned long long key = kkey[koff + q];
            int rank = q;
#pragma unroll
            for (int ol = 0; ol < 5; ol++) {
                if (ol == lvl) continue;
                int lo = 0, hi = s_cnt[ol], base = ol * 1000;
                while (lo < hi) {
                    int mid = (lo + hi) >> 1;
                    if (kkey[base + mid] > key) lo = mid + 1; else hi = mid;
                }
                rank += lo;
            }
            if (rank < POSTN) {
                int slot = kslot[koff + q];
                size_t o = (size_t)img * KTOT + slot;
                float* dst = out + ((size_t)img * POSTN + rank) * 5;
                dst[0] = sx1[o]; dst[1] = sy1[o]; dst[2] = sx2[o]; dst[3] = sy2[o];
                dst[4] = sscore[o];
            }
        }
    }

    int z0 = tK < POSTN ? tK : POSTN;
    int nz = (POSTN - z0) * 5;
    float* ob = out + (size_t)img * POSTN * 5 + (size_t)z0 * 5;
    for (int u = tid; u < nz; u += 1024) ob[u] = 0.f;
}

// ---------- host ----------

extern "C" void kernel_launch(void* const* d_in, const int* in_sizes, int n_in,
                              void* d_out, int out_size, void* d_ws, size_t ws_size,
                              hipStream_t stream) {
    const float* obj = (const float*)d_in[0];
    const float* deltas = (const float*)d_in[1];
    const float* anchors = (const float*)d_in[2];
    float* out = (float*)d_out;

    char* ws = (char*)d_ws;
    size_t off = 0;
    auto alloc = [&](size_t bytes) {
        size_t o = off;
        off += (bytes + 255) & ~(size_t)255;
        return o;
    };
    unsigned* ghist = (unsigned*)(ws + alloc((size_t)NIMG * 5 * 4096 * 4));
    int* gcnt = (int*)(ws + alloc((size_t)NIMG * BPI * 4));
    unsigned long long* gcand =
        (unsigned long long*)(ws + alloc((size_t)NIMG * BPI * CAND_CAP * 8));
    float* sx1 = (float*)(ws + alloc((size_t)NIMG * KTOT * 4));
    float* sy1 = (float*)(ws + alloc((size_t)NIMG * KTOT * 4));
    float* sx2 = (float*)(ws + alloc((size_t)NIMG * KTOT * 4));
    float* sy2 = (float*)(ws + alloc((size_t)NIMG * KTOT * 4));
    float* sscore = (float*)(ws + alloc((size_t)NIMG * KTOT * 4));
    float* cx1 = (float*)(ws + alloc((size_t)NIMG * SLOTCAP * 4));
    float* cy1 = (float*)(ws + alloc((size_t)NIMG * SLOTCAP * 4));
    float* cx2 = (float*)(ws + alloc((size_t)NIMG * SLOTCAP * 4));
    float* cy2 = (float*)(ws + alloc((size_t)NIMG * SLOTCAP * 4));
    float* car = (float*)(ws + alloc((size_t)NIMG * SLOTCAP * 4));
    unsigned long long* ckey = (unsigned long long*)(ws + alloc((size_t)NIMG * SLOTCAP * 8));
    int* cslot = (int*)(ws + alloc((size_t)NIMG * SLOTCAP * 4));
    int* cm = (int*)(ws + alloc((size_t)NIMG * 5 * 4));
    unsigned long long* maskBuf = (unsigned long long*)(ws + alloc((size_t)NIMG * 68056ULL * 8));
    unsigned long long* keepWords = (unsigned long long*)(ws + alloc((size_t)NIMG * 5 * 16 * 8));

    hipMemsetAsync(ghist, 0, (size_t)NIMG * 5 * 4096 * 4, stream);

    hist_kernel<<<dim3(NIMG * BPI), dim3(1024), 0, stream>>>(obj, ghist);
    gather_kernel<<<dim3(NIMG * BPI), dim3(1024), 0, stream>>>(obj, ghist, gcand, gcnt);
    rankdecode_kernel<<<dim3(NIMG * 5), dim3(1024), 0, stream>>>(
        deltas, anchors, gcand, gcnt, sx1, sy1, sx2, sy2, sscore,
        cx1, cy1, cx2, cy2, car, ckey, cslot, cm);
    mask_kernel<<<dim3(17, NIMG * 5), dim3(512), 0, stream>>>(cx1, cy1, cx2, cy2, car, cm,
                                                              maskBuf);
    scan_kernel<<<dim3(NIMG * 5), dim3(256), 0, stream>>>(maskBuf, cm, keepWords);
    scanout_kernel<<<dim3(NIMG), dim3(1024), 0, stream>>>(
        sx1, sy1, sx2, sy2, sscore, ckey, cslot, cm, keepWords, out);
}

// Round 8
// 227.659 us; speedup vs baseline: 1.6463x; 1.0592x over previous
//
#include <hip/hip_runtime.h>
#include <stdint.h>

#define KTOT 4507
#define POSTN 1000
#define ATOT 159882
#define NIMG 4
#define CAND_CAP 4096
#define SLOTCAP 5000  // per-image compact capacity (koff spacing = lvl*1000)
#define CHUNK 256     // rows per staged scan chunk (= 4 tiles of 64)
#define BPI 22        // hist/gather blocks per image: 15+4+1+1+1

// ---------- helpers ----------

__device__ inline unsigned fmono(float f) {
    unsigned u = __float_as_uint(f);
    return (u & 0x80000000u) ? ~u : (u | 0x80000000u);
}
__device__ inline float fmono_inv(unsigned u) {
    unsigned b = (u & 0x80000000u) ? (u ^ 0x80000000u) : ~u;
    return __uint_as_float(b);
}

__device__ inline unsigned long long shfl_u64(unsigned long long v, int src) {
    int lo = __shfl((int)(unsigned)(v & 0xFFFFFFFFULL), src);
    int hi = __shfl((int)(unsigned)(v >> 32), src);
    return ((unsigned long long)(unsigned)hi << 32) | (unsigned)lo;
}

// exclusive prefix over a 1024-thread block; warpSums = LDS int[>=16]; call uniformly.
__device__ inline int blockExclScan(int v, int* warpSums) {
    int tid = threadIdx.x;
    int lane = tid & 63, wid = tid >> 6;
    int x = v;
#pragma unroll
    for (int d = 1; d < 64; d <<= 1) {
        int y = __shfl_up(x, d);
        if (lane >= d) x += y;
    }
    if (lane == 63) warpSums[wid] = x;
    __syncthreads();
    if (wid == 0) {
        int s = (lane < 16) ? warpSums[lane] : 0;
#pragma unroll
        for (int d = 1; d < 16; d <<= 1) {
            int y = __shfl_up(s, d);
            if (lane >= d) s += y;
        }
        if (lane < 16) warpSums[lane] = s;
    }
    __syncthreads();
    int wpre = (wid == 0) ? 0 : warpSums[wid - 1];
    return wpre + (x - v);
}

__device__ __constant__ int c_lvlOff[5] = {0, 120000, 150000, 157500, 159375};
__device__ __constant__ int c_lvlN[5]   = {120000, 30000, 7500, 1875, 507};
__device__ __constant__ int c_slsz[5]   = {8000, 7500, 7500, 1875, 507};
__device__ __constant__ int c_blvl[BPI] = {0,0,0,0,0,0,0,0,0,0,0,0,0,0,0, 1,1,1,1, 2, 3, 4};
__device__ __constant__ int c_bsl[BPI]  = {0,1,2,3,4,5,6,7,8,9,10,11,12,13,14, 0,1,2,3, 0, 0, 0};
__device__ __constant__ int c_bstart[5] = {0, 15, 19, 20, 21};
__device__ __constant__ int c_bcnt[5]   = {15, 4, 1, 1, 1};

// ---------- stage A1: sliced histogram -> global per-(img,lvl) 4096-bin hist ----------

__global__ __launch_bounds__(1024) void hist_kernel(const float* __restrict__ obj,
                                                    unsigned* __restrict__ ghist) {
    __shared__ unsigned hist[4096];
    int img = blockIdx.x / BPI, b = blockIdx.x % BPI;
    int lvl = c_blvl[b], sl = c_bsl[b];
    int n = c_lvlN[lvl];
    int s0 = sl * c_slsz[lvl];
    int send = min(s0 + c_slsz[lvl], n);
    const float* src = obj + (size_t)img * ATOT + c_lvlOff[lvl];
    int tid = threadIdx.x;

    for (int i = tid; i < 4096; i += 1024) hist[i] = 0u;
    __syncthreads();

    int base = s0 + tid, last = send - 1;
    float v0 = src[min(base,        last)];
    float v1 = src[min(base + 1024, last)];
    float v2 = src[min(base + 2048, last)];
    float v3 = src[min(base + 3072, last)];
    float v4 = src[min(base + 4096, last)];
    float v5 = src[min(base + 5120, last)];
    float v6 = src[min(base + 6144, last)];
    float v7 = src[min(base + 7168, last)];
#define HIST1(U, VV) if (base + (U)*1024 < send) atomicAdd(&hist[fmono(VV) >> 20], 1u);
    HIST1(0, v0) HIST1(1, v1) HIST1(2, v2) HIST1(3, v3)
    HIST1(4, v4) HIST1(5, v5) HIST1(6, v6) HIST1(7, v7)
#undef HIST1
    __syncthreads();

    unsigned* gh = ghist + (size_t)(img * 5 + lvl) * 4096;
    for (int i = tid; i < 4096; i += 1024) {
        unsigned c = hist[i];
        if (c) atomicAdd(&gh[i], c);
    }
}

// ---------- stage A2: per-slice gather into PRIVATE segment (LDS counter only) ----------

__global__ __launch_bounds__(1024) void gather_kernel(const float* __restrict__ obj,
                                                      const unsigned* __restrict__ ghist,
                                                      unsigned long long* __restrict__ gcand,
                                                      int* __restrict__ gcnt) {
    __shared__ int s_misc[32];
    __shared__ int s_bstar, s_cnt;
    int img = blockIdx.x / BPI, b = blockIdx.x % BPI;
    int lvl = c_blvl[b], sl = c_bsl[b];
    int grp = img * 5 + lvl;
    int seg = img * BPI + b;
    int n = c_lvlN[lvl];
    int k = (lvl == 4) ? 507 : 1000;
    int s0 = sl * c_slsz[lvl];
    int send = min(s0 + c_slsz[lvl], n);
    const float* src = obj + (size_t)img * ATOT + c_lvlOff[lvl];
    int tid = threadIdx.x;
    int lane = tid & 63;

    if (tid == 0) s_cnt = 0;

    const uint4* gh4 = (const uint4*)(ghist + (size_t)grp * 4096);
    uint4 cc = gh4[tid];
    int mysum = (int)(cc.x + cc.y + cc.z + cc.w);
    int excl = blockExclScan(mysum, s_misc);
    int target = n - k;
    {
        int P = excl;
        if ((int)cc.x > 0 && P <= target && target < P + (int)cc.x) s_bstar = 4 * tid + 0;
        P += (int)cc.x;
        if ((int)cc.y > 0 && P <= target && target < P + (int)cc.y) s_bstar = 4 * tid + 1;
        P += (int)cc.y;
        if ((int)cc.z > 0 && P <= target && target < P + (int)cc.z) s_bstar = 4 * tid + 2;
        P += (int)cc.z;
        if ((int)cc.w > 0 && P <= target && target < P + (int)cc.w) s_bstar = 4 * tid + 3;
    }
    __syncthreads();
    int bstar = s_bstar;

    unsigned long long* gc = gcand + (size_t)seg * CAND_CAP;
    int base = s0 + tid, last = send - 1;
    float v0 = src[min(base,        last)];
    float v1 = src[min(base + 1024, last)];
    float v2 = src[min(base + 2048, last)];
    float v3 = src[min(base + 3072, last)];
    float v4 = src[min(base + 4096, last)];
    float v5 = src[min(base + 5120, last)];
    float v6 = src[min(base + 6144, last)];
    float v7 = src[min(base + 7168, last)];
#define PUSH1(U, VV)                                                                     \
    {                                                                                    \
        int ix = base + (U) * 1024;                                                      \
        unsigned key = fmono(VV);                                                        \
        bool s = (ix < send) && ((int)(key >> 20) >= bstar);                             \
        unsigned long long mk = __ballot(s);                                             \
        if (mk) {                                                                        \
            int pre = __popcll(mk & ((1ULL << lane) - 1ULL));                            \
            int ldr = __builtin_ctzll(mk);                                               \
            int basew = 0;                                                               \
            if (lane == ldr) basew = atomicAdd(&s_cnt, __popcll(mk));                    \
            basew = __shfl(basew, ldr);                                                  \
            if (s) {                                                                     \
                int pos = basew + pre;                                                   \
                if (pos < CAND_CAP)                                                      \
                    gc[pos] = ((unsigned long long)key << 32) | (unsigned)(~(unsigned)ix); \
            }                                                                            \
        }                                                                                \
    }
    PUSH1(0, v0) PUSH1(1, v1) PUSH1(2, v2) PUSH1(3, v3)
    PUSH1(4, v4) PUSH1(5, v5) PUSH1(6, v6) PUSH1(7, v7)
#undef PUSH1
    __syncthreads();
    if (tid == 0) gcnt[seg] = min(s_cnt, CAND_CAP);
}

// ---------- stage B: concat segments + bitonic sort + decode + compaction (fused) ----------

__global__ __launch_bounds__(1024) void rankdecode_kernel(
    const float* __restrict__ deltas, const float* __restrict__ anchors,
    const unsigned long long* __restrict__ gcand, const int* __restrict__ gcnt,
    float* __restrict__ sx1, float* __restrict__ sy1, float* __restrict__ sx2,
    float* __restrict__ sy2, float* __restrict__ sscore,
    float* __restrict__ cx1, float* __restrict__ cy1, float* __restrict__ cx2,
    float* __restrict__ cy2, float* __restrict__ car,
    unsigned long long* __restrict__ ckey, int* __restrict__ cslot, int* __restrict__ cm) {
    __shared__ unsigned long long ck[CAND_CAP];
    __shared__ int s_warp[32];

    int grp = blockIdx.x;
    int img = grp / 5, lvl = grp % 5;
    int kn = (lvl == 4) ? 507 : 1000;
    int koff = lvl * 1000;
    int tid = threadIdx.x;

    int bs = c_bstart[lvl], bc = c_bcnt[lvl];
    int pref = 0;
    for (int s = 0; s < bc; s++) {
        int c = gcnt[img * BPI + bs + s];
        const unsigned long long* segp = gcand + (size_t)(img * BPI + bs + s) * CAND_CAP;
        for (int i = tid; i < c; i += 1024) {
            int d = pref + i;
            if (d < CAND_CAP) ck[d] = segp[i];
        }
        pref += c;
    }
    int m = min(pref, CAND_CAP);
    int P = 512;
    while (P < m) P <<= 1;
    for (int i = m + tid; i < P; i += 1024) ck[i] = 0ULL;
    __syncthreads();

    for (unsigned kk = 2; kk <= (unsigned)P; kk <<= 1) {
        for (unsigned j = kk >> 1; j > 0; j >>= 1) {
            for (unsigned i = (unsigned)tid; i < (unsigned)P; i += 1024) {
                unsigned ixj = i ^ j;
                if (ixj > i) {
                    unsigned long long a = ck[i], b = ck[ixj];
                    bool up = ((i & kk) == 0);
                    if ((a > b) == up) { ck[i] = b; ck[ixj] = a; }
                }
            }
            __syncthreads();
        }
    }

    int r = tid;
    size_t o = (size_t)img * KTOT + koff + r;
    float x1 = 0.f, y1 = 0.f, x2 = 0.f, y2 = 0.f, s = 0.f;
    int valid = 0;
    if (r < kn) {
        unsigned long long key = ck[P - 1 - r];
        int idx = c_lvlOff[lvl] + (int)(~(unsigned)key);
        float logit = fmono_inv((unsigned)(key >> 32));
        float ef = (float)exp(-(double)logit);
        s = 1.0f / __fadd_rn(1.0f, ef);
        float a0 = anchors[(size_t)idx * 4 + 0], a1 = anchors[(size_t)idx * 4 + 1];
        float a2 = anchors[(size_t)idx * 4 + 2], a3 = anchors[(size_t)idx * 4 + 3];
        const float* dp = deltas + ((size_t)img * ATOT + idx) * 4;
        float dx = dp[0], dy = dp[1];
        const float BCLIP = 4.135166556742356f;  // log(1000/16)
        float dw = fminf(dp[2], BCLIP), dh = fminf(dp[3], BCLIP);
        float wa = __fsub_rn(a2, a0), ha = __fsub_rn(a3, a1);
        float cxa = __fadd_rn(a0, __fmul_rn(0.5f, wa));
        float cya = __fadd_rn(a1, __fmul_rn(0.5f, ha));
        float cx = __fadd_rn(__fmul_rn(dx, wa), cxa);
        float cy = __fadd_rn(__fmul_rn(dy, ha), cya);
        float w = __fmul_rn((float)exp((double)dw), wa);
        float h = __fmul_rn((float)exp((double)dh), ha);
        x1 = __fsub_rn(cx, __fmul_rn(0.5f, w));
        y1 = __fsub_rn(cy, __fmul_rn(0.5f, h));
        x2 = __fadd_rn(cx, __fmul_rn(0.5f, w));
        y2 = __fadd_rn(cy, __fmul_rn(0.5f, h));
        x1 = fminf(fmaxf(x1, 0.0f), 800.0f);
        y1 = fminf(fmaxf(y1, 0.0f), 800.0f);
        x2 = fminf(fmaxf(x2, 0.0f), 800.0f);
        y2 = fminf(fmaxf(y2, 0.0f), 800.0f);
        valid = (__fsub_rn(x2, x1) >= 0.001f) && (__fsub_rn(y2, y1) >= 0.001f) && (s >= 0.0f);
        sx1[o] = x1; sy1[o] = y1; sx2[o] = x2; sy2[o] = y2; sscore[o] = s;
    }

    int pos = blockExclScan(valid, s_warp);
    if (valid) {
        float lf = 1000.0f * (float)lvl;
        size_t cb = (size_t)img * SLOTCAP + koff + pos;
        float ox1 = __fadd_rn(x1, lf);
        float oy1 = __fadd_rn(y1, lf);
        float ox2 = __fadd_rn(x2, lf);
        float oy2 = __fadd_rn(y2, lf);
        cx1[cb] = ox1; cy1[cb] = oy1; cx2[cb] = ox2; cy2[cb] = oy2;
        car[cb] = __fmul_rn(__fsub_rn(ox2, ox1), __fsub_rn(oy2, oy1));
        int p = koff + r;
        ckey[cb] = ((unsigned long long)fmono(s) << 32) | (unsigned)(~(unsigned)p);
        cslot[cb] = p;
    }
    if (tid == 1023) cm[grp] = pos + valid;
}

// ---------- stage C: mask build (row words + TRANSPOSED diagonal tiles) ----------

__global__ __launch_bounds__(512) void mask_kernel(
    const float* __restrict__ cx1, const float* __restrict__ cy1,
    const float* __restrict__ cx2, const float* __restrict__ cy2,
    const float* __restrict__ car, const int* __restrict__ cm,
    unsigned long long* __restrict__ maskBuf, unsigned long long* __restrict__ dtileBuf) {
    __shared__ float lx1[1000], ly1[1000], lx2[1000], ly2[1000], lar[1000];
    int iq = blockIdx.y;
    int img = iq / 5, lvl = iq % 5;
    int m = cm[iq];
    int W = (m + 63) >> 6;
    int T = (W * (W + 1)) >> 1;
    int tbase = blockIdx.x * 8;
    if (tbase >= T) return;

    size_t cb0 = (size_t)img * SLOTCAP + lvl * 1000;
    for (int q = threadIdx.x; q < m; q += 512) {
        lx1[q] = cx1[cb0 + q]; ly1[q] = cy1[cb0 + q];
        lx2[q] = cx2[cb0 + q]; ly2[q] = cy2[cb0 + q];
        lar[q] = car[cb0 + q];
    }
    __syncthreads();

    int wv = threadIdx.x >> 6, lane = threadIdx.x & 63;
    int t = tbase + wv;
    if (t >= T) return;
    int w = (int)((sqrtf(8.0f * (float)t + 1.0f) - 1.0f) * 0.5f);
    while (((w + 1) * (w + 2)) / 2 <= t) w++;
    while ((w * (w + 1)) / 2 > t) w--;
    int c = t - ((w * (w + 1)) >> 1);

    size_t mOff = (size_t)img * 68056 + (size_t)lvl * 16000;
    int Wa = (lvl == 4) ? 8 : 16;
    unsigned long long* M = maskBuf + mOff;

    int j = (w << 6) + lane;
    bool jv = j < m;
    float jx1 = jv ? lx1[j] : 0.f, jy1 = jv ? ly1[j] : 0.f;
    float jx2 = jv ? lx2[j] : 0.f, jy2 = jv ? ly2[j] : 0.f;
    float jar = jv ? lar[j] : 0.f;

    unsigned long long myword = 0ULL;
    unsigned long long tcol = 0ULL;  // transposed: bit i = (row i0+i suppresses col j)
    int i0 = c << 6, i1 = min(i0 + 64, m);
    for (int i = i0; i < i1; i++) {
        float ix1 = lx1[i], iy1 = ly1[i], ix2 = lx2[i], iy2 = ly2[i], iar = lar[i];
        float ltx = fmaxf(ix1, jx1);
        float lty = fmaxf(iy1, jy1);
        float rbx = fminf(ix2, jx2);
        float rby = fminf(iy2, jy2);
        float wq = fmaxf(__fsub_rn(rbx, ltx), 0.0f);
        float hq = fmaxf(__fsub_rn(rby, lty), 0.0f);
        float inter = __fmul_rn(wq, hq);
        float uni = __fsub_rn(__fadd_rn(iar, jar), inter);
        float iou = inter / uni;  // keep IEEE div: decisions must match reference exactly
        bool bit = jv && (j > i) && (iou > 0.7f);
        tcol |= (unsigned long long)bit << (i - i0);
        unsigned long long bal = __ballot(bit);
        if (lane == (i & 63)) myword = bal;
    }
    int irow = i0 + lane;
    if (irow < i1) M[(size_t)irow * Wa + w] = myword;
    if (w == c) dtileBuf[((size_t)iq * 16 + w) * 64 + lane] = tcol;
}

// ---------- stage C2: tile-serial greedy scan — register-only dependency chain ----------
// wave 0: per 64-row tile, resolve within-tile greedy via per-lane deadbit + ballot
// (operands in VGPRs; zero loads in the chain), then data-parallel OR of alive rows'
// mask words into per-lane remv. waves 1-3 stage mask chunks to LDS.

__global__ __launch_bounds__(256, 1) void scan_kernel(
    const unsigned long long* __restrict__ maskBuf,
    const unsigned long long* __restrict__ dtileBuf, const int* __restrict__ cm,
    unsigned long long* __restrict__ keepWords) {
    __shared__ unsigned long long sbuf[2][CHUNK * 16];  // 64 KB double buffer
    int grp = blockIdx.x;
    int img = grp / 5, lvl = grp % 5;
    int m = cm[grp];
    int W = (m + 63) >> 6;
    int Wa = (lvl == 4) ? 8 : 16;
    const unsigned long long* M = maskBuf + (size_t)img * 68056 + (size_t)lvl * 16000;
    const unsigned long long* D = dtileBuf + (size_t)grp * 16 * 64;
    int tid = threadIdx.x;
    int wv = tid >> 6, lane = tid & 63;
    int nch = (m + CHUNK - 1) / CHUNK;

    {
        int words0 = min(CHUNK, m) * Wa;
        for (int u = tid; u < words0; u += 256) sbuf[0][u] = M[u];
    }

    unsigned long long acc = 0ULL;  // wave 0, lane w: removal word w
    unsigned long long dt0 = 0, dt1 = 0, dt2 = 0, dt3 = 0;
    if (wv == 0) {  // prefetch chunk 0's diagonal tiles
        if (0 < W) dt0 = D[0 * 64 + lane];
        if (1 < W) dt1 = D[1 * 64 + lane];
        if (2 < W) dt2 = D[2 * 64 + lane];
        if (3 < W) dt3 = D[3 * 64 + lane];
    }
    __syncthreads();

    for (int ch = 0; ch < nch; ch++) {
        if (wv > 0 && ch + 1 < nch) {  // waves 1-3: stage next chunk
            int rbase = (ch + 1) * CHUNK;
            int wordsN = (min(rbase + CHUNK, m) - rbase) * Wa;
            const unsigned long long* srcp = M + (size_t)rbase * Wa;
            unsigned long long* dstp = sbuf[(ch + 1) & 1];
            for (int u = tid - 64; u < wordsN; u += 192) dstp[u] = srcp[u];
        }
        if (wv == 0) {
            // prefetch next chunk's diagonal tiles
            unsigned long long nt0 = 0, nt1 = 0, nt2 = 0, nt3 = 0;
            if (ch + 1 < nch) {
                int tb = (ch + 1) * 4;
                if (tb + 0 < W) nt0 = D[(tb + 0) * 64 + lane];
                if (tb + 1 < W) nt1 = D[(tb + 1) * 64 + lane];
                if (tb + 2 < W) nt2 = D[(tb + 2) * 64 + lane];
                if (tb + 3 < W) nt3 = D[(tb + 3) * 64 + lane];
            }
            const unsigned long long* buf = sbuf[ch & 1];
#define TILE(DT, Q)                                                                      \
            {                                                                            \
                int t = ch * 4 + (Q);                                                    \
                if (t < W) {                                                             \
                    int iend = min(64, m - (t << 6));                                    \
                    unsigned long long rw = shfl_u64(acc, t);                            \
                    bool deadbit = ((rw >> lane) & 1ULL) != 0ULL;                        \
                    unsigned long long C = (DT);                                         \
                    _Pragma("unroll")                                                    \
                    for (int i = 0; i < 64; i++) {                                       \
                        unsigned long long bal = __ballot(deadbit);                      \
                        bool alive = ((bal >> i) & 1ULL) == 0ULL;                        \
                        deadbit = deadbit || (alive && (((C >> i) & 1ULL) != 0ULL));     \
                    }                                                                    \
                    unsigned long long A = __ballot(!deadbit);                           \
                    if (lane == 0) keepWords[grp * 16 + t] = A;                          \
                    if (lane < W) {                                                      \
                        int rowb = (t - ch * 4) << 6;                                    \
                        for (int i = 0; i < iend; i++) {                                 \
                            unsigned long long v = buf[(size_t)(rowb + i) * Wa + lane];  \
                            unsigned long long g = (A >> i) & 1ULL;                      \
                            acc |= v & (0ULL - g);                                       \
                        }                                                                \
                    }                                                                    \
                }                                                                        \
            }
            TILE(dt0, 0) TILE(dt1, 1) TILE(dt2, 2) TILE(dt3, 3)
#undef TILE
            dt0 = nt0; dt1 = nt1; dt2 = nt2; dt3 = nt3;
        }
        __syncthreads();
    }
}

// ---------- stage D: compaction + global rank + output ----------

__global__ __launch_bounds__(1024) void scanout_kernel(
    const float* __restrict__ sx1, const float* __restrict__ sy1,
    const float* __restrict__ sx2, const float* __restrict__ sy2,
    const float* __restrict__ sscore,
    const unsigned long long* __restrict__ ckey, const int* __restrict__ cslot,
    const int* __restrict__ cm, const unsigned long long* __restrict__ keepWords,
    float* __restrict__ out) {
    __shared__ unsigned long long kkey[SLOTCAP];
    __shared__ int kslot[SLOTCAP];
    __shared__ int s_warp[32];
    __shared__ int s_cnt[5];

    int img = blockIdx.x, tid = threadIdx.x;

    for (int lvl = 0; lvl < 5; lvl++) {
        int m = cm[img * 5 + lvl];
        int koff = lvl * 1000;
        int flag = 0;
        if (tid < m)
            flag = (int)((keepWords[(img * 5 + lvl) * 16 + (tid >> 6)] >> (tid & 63)) & 1ULL);
        int pos = blockExclScan(flag, s_warp);
        if (flag) {
            size_t cb = (size_t)img * SLOTCAP + koff + tid;
            kkey[koff + pos] = ckey[cb];
            kslot[koff + pos] = cslot[cb];
        }
        if (tid == 1023) s_cnt[lvl] = pos + flag;
        __syncthreads();
    }

    int tK = s_cnt[0] + s_cnt[1] + s_cnt[2] + s_cnt[3] + s_cnt[4];

    for (int lvl = 0; lvl < 5; lvl++) {
        int Kc = s_cnt[lvl];
        int koff = lvl * 1000;
        for (int q = tid; q < Kc; q += 1024) {
            unsigned long long key = kkey[koff + q];
            int rank = q;
#pragma unroll
            for (int ol = 0; ol < 5; ol++) {
                if (ol == lvl) continue;
                int lo = 0, hi = s_cnt[ol], base = ol * 1000;
                while (lo < hi) {
                    int mid = (lo + hi) >> 1;
                    if (kkey[base + mid] > key) lo = mid + 1; else hi = mid;
                }
                rank += lo;
            }
            if (rank < POSTN) {
                int slot = kslot[koff + q];
                size_t o = (size_t)img * KTOT + slot;
                float* dst = out + ((size_t)img * POSTN + rank) * 5;
                dst[0] = sx1[o]; dst[1] = sy1[o]; dst[2] = sx2[o]; dst[3] = sy2[o];
                dst[4] = sscore[o];
            }
        }
    }

    int z0 = tK < POSTN ? tK : POSTN;
    int nz = (POSTN - z0) * 5;
    float* ob = out + (size_t)img * POSTN * 5 + (size_t)z0 * 5;
    for (int u = tid; u < nz; u += 1024) ob[u] = 0.f;
}

// ---------- host ----------

extern "C" void kernel_launch(void* const* d_in, const int* in_sizes, int n_in,
                              void* d_out, int out_size, void* d_ws, size_t ws_size,
                              hipStream_t stream) {
    const float* obj = (const float*)d_in[0];
    const float* deltas = (const float*)d_in[1];
    const float* anchors = (const float*)d_in[2];
    float* out = (float*)d_out;

    char* ws = (char*)d_ws;
    size_t off = 0;
    auto alloc = [&](size_t bytes) {
        size_t o = off;
        off += (bytes + 255) & ~(size_t)255;
        return o;
    };
    unsigned* ghist = (unsigned*)(ws + alloc((size_t)NIMG * 5 * 4096 * 4));
    int* gcnt = (int*)(ws + alloc((size_t)NIMG * BPI * 4));
    unsigned long long* gcand =
        (unsigned long long*)(ws + alloc((size_t)NIMG * BPI * CAND_CAP * 8));
    float* sx1 = (float*)(ws + alloc((size_t)NIMG * KTOT * 4));
    float* sy1 = (float*)(ws + alloc((size_t)NIMG * KTOT * 4));
    float* sx2 = (float*)(ws + alloc((size_t)NIMG * KTOT * 4));
    float* sy2 = (float*)(ws + alloc((size_t)NIMG * KTOT * 4));
    float* sscore = (float*)(ws + alloc((size_t)NIMG * KTOT * 4));
    float* cx1 = (float*)(ws + alloc((size_t)NIMG * SLOTCAP * 4));
    float* cy1 = (float*)(ws + alloc((size_t)NIMG * SLOTCAP * 4));
    float* cx2 = (float*)(ws + alloc((size_t)NIMG * SLOTCAP * 4));
    float* cy2 = (float*)(ws + alloc((size_t)NIMG * SLOTCAP * 4));
    float* car = (float*)(ws + alloc((size_t)NIMG * SLOTCAP * 4));
    unsigned long long* ckey = (unsigned long long*)(ws + alloc((size_t)NIMG * SLOTCAP * 8));
    int* cslot = (int*)(ws + alloc((size_t)NIMG * SLOTCAP * 4));
    int* cm = (int*)(ws + alloc((size_t)NIMG * 5 * 4));
    unsigned long long* maskBuf = (unsigned long long*)(ws + alloc((size_t)NIMG * 68056ULL * 8));
    unsigned long long* dtileBuf =
        (unsigned long long*)(ws + alloc((size_t)NIMG * 5 * 16 * 64 * 8));
    unsigned long long* keepWords = (unsigned long long*)(ws + alloc((size_t)NIMG * 5 * 16 * 8));

    hipMemsetAsync(ghist, 0, (size_t)NIMG * 5 * 4096 * 4, stream);

    hist_kernel<<<dim3(NIMG * BPI), dim3(1024), 0, stream>>>(obj, ghist);
    gather_kernel<<<dim3(NIMG * BPI), dim3(1024), 0, stream>>>(obj, ghist, gcand, gcnt);
    rankdecode_kernel<<<dim3(NIMG * 5), dim3(1024), 0, stream>>>(
        deltas, anchors, gcand, gcnt, sx1, sy1, sx2, sy2, sscore,
        cx1, cy1, cx2, cy2, car, ckey, cslot, cm);
    mask_kernel<<<dim3(17, NIMG * 5), dim3(512), 0, stream>>>(cx1, cy1, cx2, cy2, car, cm,
                                                              maskBuf, dtileBuf);
    scan_kernel<<<dim3(NIMG * 5), dim3(256), 0, stream>>>(maskBuf, dtileBuf, cm, keepWords);
    scanout_kernel<<<dim3(NIMG), dim3(1024), 0, stream>>>(
        sx1, sy1, sx2, sy2, sscore, ckey, cslot, cm, keepWords, out);
}

// Round 9
// 224.603 us; speedup vs baseline: 1.6687x; 1.0136x over previous
//
#include <hip/hip_runtime.h>
#include <stdint.h>

#define KTOT 4507
#define POSTN 1000
#define ATOT 159882
#define NIMG 4
#define CAND_CAP 4096
#define SLOTCAP 5000  // per-image compact capacity (koff spacing = lvl*1000)
#define CHUNK 256     // rows per staged scan chunk (= 4 tiles of 64)
#define BPI 22        // hist/gather blocks per image: 15+4+1+1+1

// ---------- helpers ----------

__device__ inline unsigned fmono(float f) {
    unsigned u = __float_as_uint(f);
    return (u & 0x80000000u) ? ~u : (u | 0x80000000u);
}
__device__ inline float fmono_inv(unsigned u) {
    unsigned b = (u & 0x80000000u) ? (u ^ 0x80000000u) : ~u;
    return __uint_as_float(b);
}

__device__ inline unsigned long long shfl_u64(unsigned long long v, int src) {
    int lo = __shfl((int)(unsigned)(v & 0xFFFFFFFFULL), src);
    int hi = __shfl((int)(unsigned)(v >> 32), src);
    return ((unsigned long long)(unsigned)hi << 32) | (unsigned)lo;
}

// exclusive prefix over a 1024-thread block; warpSums = LDS int[>=16]; call uniformly.
__device__ inline int blockExclScan(int v, int* warpSums) {
    int tid = threadIdx.x;
    int lane = tid & 63, wid = tid >> 6;
    int x = v;
#pragma unroll
    for (int d = 1; d < 64; d <<= 1) {
        int y = __shfl_up(x, d);
        if (lane >= d) x += y;
    }
    if (lane == 63) warpSums[wid] = x;
    __syncthreads();
    if (wid == 0) {
        int s = (lane < 16) ? warpSums[lane] : 0;
#pragma unroll
        for (int d = 1; d < 16; d <<= 1) {
            int y = __shfl_up(s, d);
            if (lane >= d) s += y;
        }
        if (lane < 16) warpSums[lane] = s;
    }
    __syncthreads();
    int wpre = (wid == 0) ? 0 : warpSums[wid - 1];
    return wpre + (x - v);
}

__device__ __constant__ int c_lvlOff[5] = {0, 120000, 150000, 157500, 159375};
__device__ __constant__ int c_lvlN[5]   = {120000, 30000, 7500, 1875, 507};
__device__ __constant__ int c_slsz[5]   = {8000, 7500, 7500, 1875, 507};
__device__ __constant__ int c_blvl[BPI] = {0,0,0,0,0,0,0,0,0,0,0,0,0,0,0, 1,1,1,1, 2, 3, 4};
__device__ __constant__ int c_bsl[BPI]  = {0,1,2,3,4,5,6,7,8,9,10,11,12,13,14, 0,1,2,3, 0, 0, 0};
__device__ __constant__ int c_bstart[5] = {0, 15, 19, 20, 21};
__device__ __constant__ int c_bcnt[5]   = {15, 4, 1, 1, 1};

// ---------- stage A1: sliced histogram -> global per-(img,lvl) 4096-bin hist ----------

__global__ __launch_bounds__(1024) void hist_kernel(const float* __restrict__ obj,
                                                    unsigned* __restrict__ ghist) {
    __shared__ unsigned hist[4096];
    int img = blockIdx.x / BPI, b = blockIdx.x % BPI;
    int lvl = c_blvl[b], sl = c_bsl[b];
    int n = c_lvlN[lvl];
    int s0 = sl * c_slsz[lvl];
    int send = min(s0 + c_slsz[lvl], n);
    const float* src = obj + (size_t)img * ATOT + c_lvlOff[lvl];
    int tid = threadIdx.x;

    for (int i = tid; i < 4096; i += 1024) hist[i] = 0u;
    __syncthreads();

    int base = s0 + tid, last = send - 1;
    float v0 = src[min(base,        last)];
    float v1 = src[min(base + 1024, last)];
    float v2 = src[min(base + 2048, last)];
    float v3 = src[min(base + 3072, last)];
    float v4 = src[min(base + 4096, last)];
    float v5 = src[min(base + 5120, last)];
    float v6 = src[min(base + 6144, last)];
    float v7 = src[min(base + 7168, last)];
#define HIST1(U, VV) if (base + (U)*1024 < send) atomicAdd(&hist[fmono(VV) >> 20], 1u);
    HIST1(0, v0) HIST1(1, v1) HIST1(2, v2) HIST1(3, v3)
    HIST1(4, v4) HIST1(5, v5) HIST1(6, v6) HIST1(7, v7)
#undef HIST1
    __syncthreads();

    unsigned* gh = ghist + (size_t)(img * 5 + lvl) * 4096;
    for (int i = tid; i < 4096; i += 1024) {
        unsigned c = hist[i];
        if (c) atomicAdd(&gh[i], c);
    }
}

// ---------- stage A2: per-slice gather into PRIVATE segment (LDS counter only) ----------

__global__ __launch_bounds__(1024) void gather_kernel(const float* __restrict__ obj,
                                                      const unsigned* __restrict__ ghist,
                                                      unsigned long long* __restrict__ gcand,
                                                      int* __restrict__ gcnt) {
    __shared__ int s_misc[32];
    __shared__ int s_bstar, s_cnt;
    int img = blockIdx.x / BPI, b = blockIdx.x % BPI;
    int lvl = c_blvl[b], sl = c_bsl[b];
    int grp = img * 5 + lvl;
    int seg = img * BPI + b;
    int n = c_lvlN[lvl];
    int k = (lvl == 4) ? 507 : 1000;
    int s0 = sl * c_slsz[lvl];
    int send = min(s0 + c_slsz[lvl], n);
    const float* src = obj + (size_t)img * ATOT + c_lvlOff[lvl];
    int tid = threadIdx.x;
    int lane = tid & 63;

    if (tid == 0) s_cnt = 0;

    const uint4* gh4 = (const uint4*)(ghist + (size_t)grp * 4096);
    uint4 cc = gh4[tid];
    int mysum = (int)(cc.x + cc.y + cc.z + cc.w);
    int excl = blockExclScan(mysum, s_misc);
    int target = n - k;
    {
        int P = excl;
        if ((int)cc.x > 0 && P <= target && target < P + (int)cc.x) s_bstar = 4 * tid + 0;
        P += (int)cc.x;
        if ((int)cc.y > 0 && P <= target && target < P + (int)cc.y) s_bstar = 4 * tid + 1;
        P += (int)cc.y;
        if ((int)cc.z > 0 && P <= target && target < P + (int)cc.z) s_bstar = 4 * tid + 2;
        P += (int)cc.z;
        if ((int)cc.w > 0 && P <= target && target < P + (int)cc.w) s_bstar = 4 * tid + 3;
    }
    __syncthreads();
    int bstar = s_bstar;

    unsigned long long* gc = gcand + (size_t)seg * CAND_CAP;
    int base = s0 + tid, last = send - 1;
    float v0 = src[min(base,        last)];
    float v1 = src[min(base + 1024, last)];
    float v2 = src[min(base + 2048, last)];
    float v3 = src[min(base + 3072, last)];
    float v4 = src[min(base + 4096, last)];
    float v5 = src[min(base + 5120, last)];
    float v6 = src[min(base + 6144, last)];
    float v7 = src[min(base + 7168, last)];
#define PUSH1(U, VV)                                                                     \
    {                                                                                    \
        int ix = base + (U) * 1024;                                                      \
        unsigned key = fmono(VV);                                                        \
        bool s = (ix < send) && ((int)(key >> 20) >= bstar);                             \
        unsigned long long mk = __ballot(s);                                             \
        if (mk) {                                                                        \
            int pre = __popcll(mk & ((1ULL << lane) - 1ULL));                            \
            int ldr = __builtin_ctzll(mk);                                               \
            int basew = 0;                                                               \
            if (lane == ldr) basew = atomicAdd(&s_cnt, __popcll(mk));                    \
            basew = __shfl(basew, ldr);                                                  \
            if (s) {                                                                     \
                int pos = basew + pre;                                                   \
                if (pos < CAND_CAP)                                                      \
                    gc[pos] = ((unsigned long long)key << 32) | (unsigned)(~(unsigned)ix); \
            }                                                                            \
        }                                                                                \
    }
    PUSH1(0, v0) PUSH1(1, v1) PUSH1(2, v2) PUSH1(3, v3)
    PUSH1(4, v4) PUSH1(5, v5) PUSH1(6, v6) PUSH1(7, v7)
#undef PUSH1
    __syncthreads();
    if (tid == 0) gcnt[seg] = min(s_cnt, CAND_CAP);
}

// ---------- stage B: concat segments + bitonic sort + decode + compaction (fused) ----------

__global__ __launch_bounds__(1024) void rankdecode_kernel(
    const float* __restrict__ deltas, const float* __restrict__ anchors,
    const unsigned long long* __restrict__ gcand, const int* __restrict__ gcnt,
    float* __restrict__ sx1, float* __restrict__ sy1, float* __restrict__ sx2,
    float* __restrict__ sy2, float* __restrict__ sscore,
    float* __restrict__ cx1, float* __restrict__ cy1, float* __restrict__ cx2,
    float* __restrict__ cy2, float* __restrict__ car,
    unsigned long long* __restrict__ ckey, int* __restrict__ cslot, int* __restrict__ cm) {
    __shared__ unsigned long long ck[CAND_CAP];
    __shared__ int s_warp[32];

    int grp = blockIdx.x;
    int img = grp / 5, lvl = grp % 5;
    int kn = (lvl == 4) ? 507 : 1000;
    int koff = lvl * 1000;
    int tid = threadIdx.x;

    int bs = c_bstart[lvl], bc = c_bcnt[lvl];
    int pref = 0;
    for (int s = 0; s < bc; s++) {
        int c = gcnt[img * BPI + bs + s];
        const unsigned long long* segp = gcand + (size_t)(img * BPI + bs + s) * CAND_CAP;
        for (int i = tid; i < c; i += 1024) {
            int d = pref + i;
            if (d < CAND_CAP) ck[d] = segp[i];
        }
        pref += c;
    }
    int m = min(pref, CAND_CAP);
    int P = 512;
    while (P < m) P <<= 1;
    for (int i = m + tid; i < P; i += 1024) ck[i] = 0ULL;
    __syncthreads();

    for (unsigned kk = 2; kk <= (unsigned)P; kk <<= 1) {
        for (unsigned j = kk >> 1; j > 0; j >>= 1) {
            for (unsigned i = (unsigned)tid; i < (unsigned)P; i += 1024) {
                unsigned ixj = i ^ j;
                if (ixj > i) {
                    unsigned long long a = ck[i], b = ck[ixj];
                    bool up = ((i & kk) == 0);
                    if ((a > b) == up) { ck[i] = b; ck[ixj] = a; }
                }
            }
            __syncthreads();
        }
    }

    int r = tid;
    size_t o = (size_t)img * KTOT + koff + r;
    float x1 = 0.f, y1 = 0.f, x2 = 0.f, y2 = 0.f, s = 0.f;
    int valid = 0;
    if (r < kn) {
        unsigned long long key = ck[P - 1 - r];
        int idx = c_lvlOff[lvl] + (int)(~(unsigned)key);
        float logit = fmono_inv((unsigned)(key >> 32));
        float ef = (float)exp(-(double)logit);
        s = 1.0f / __fadd_rn(1.0f, ef);
        float a0 = anchors[(size_t)idx * 4 + 0], a1 = anchors[(size_t)idx * 4 + 1];
        float a2 = anchors[(size_t)idx * 4 + 2], a3 = anchors[(size_t)idx * 4 + 3];
        const float* dp = deltas + ((size_t)img * ATOT + idx) * 4;
        float dx = dp[0], dy = dp[1];
        const float BCLIP = 4.135166556742356f;  // log(1000/16)
        float dw = fminf(dp[2], BCLIP), dh = fminf(dp[3], BCLIP);
        float wa = __fsub_rn(a2, a0), ha = __fsub_rn(a3, a1);
        float cxa = __fadd_rn(a0, __fmul_rn(0.5f, wa));
        float cya = __fadd_rn(a1, __fmul_rn(0.5f, ha));
        float cx = __fadd_rn(__fmul_rn(dx, wa), cxa);
        float cy = __fadd_rn(__fmul_rn(dy, ha), cya);
        float w = __fmul_rn((float)exp((double)dw), wa);
        float h = __fmul_rn((float)exp((double)dh), ha);
        x1 = __fsub_rn(cx, __fmul_rn(0.5f, w));
        y1 = __fsub_rn(cy, __fmul_rn(0.5f, h));
        x2 = __fadd_rn(cx, __fmul_rn(0.5f, w));
        y2 = __fadd_rn(cy, __fmul_rn(0.5f, h));
        x1 = fminf(fmaxf(x1, 0.0f), 800.0f);
        y1 = fminf(fmaxf(y1, 0.0f), 800.0f);
        x2 = fminf(fmaxf(x2, 0.0f), 800.0f);
        y2 = fminf(fmaxf(y2, 0.0f), 800.0f);
        valid = (__fsub_rn(x2, x1) >= 0.001f) && (__fsub_rn(y2, y1) >= 0.001f) && (s >= 0.0f);
        sx1[o] = x1; sy1[o] = y1; sx2[o] = x2; sy2[o] = y2; sscore[o] = s;
    }

    int pos = blockExclScan(valid, s_warp);
    if (valid) {
        float lf = 1000.0f * (float)lvl;
        size_t cb = (size_t)img * SLOTCAP + koff + pos;
        float ox1 = __fadd_rn(x1, lf);
        float oy1 = __fadd_rn(y1, lf);
        float ox2 = __fadd_rn(x2, lf);
        float oy2 = __fadd_rn(y2, lf);
        cx1[cb] = ox1; cy1[cb] = oy1; cx2[cb] = ox2; cy2[cb] = oy2;
        car[cb] = __fmul_rn(__fsub_rn(ox2, ox1), __fsub_rn(oy2, oy1));
        int p = koff + r;
        ckey[cb] = ((unsigned long long)fmono(s) << 32) | (unsigned)(~(unsigned)p);
        cslot[cb] = p;
    }
    if (tid == 1023) cm[grp] = pos + valid;
}

// ---------- stage C: mask build (row words + TRANSPOSED diagonal tiles) ----------

__global__ __launch_bounds__(512) void mask_kernel(
    const float* __restrict__ cx1, const float* __restrict__ cy1,
    const float* __restrict__ cx2, const float* __restrict__ cy2,
    const float* __restrict__ car, const int* __restrict__ cm,
    unsigned long long* __restrict__ maskBuf, unsigned long long* __restrict__ dtileBuf) {
    __shared__ float lx1[1000], ly1[1000], lx2[1000], ly2[1000], lar[1000];
    int iq = blockIdx.y;
    int img = iq / 5, lvl = iq % 5;
    int m = cm[iq];
    int W = (m + 63) >> 6;
    int T = (W * (W + 1)) >> 1;
    int tbase = blockIdx.x * 8;
    if (tbase >= T) return;

    size_t cb0 = (size_t)img * SLOTCAP + lvl * 1000;
    for (int q = threadIdx.x; q < m; q += 512) {
        lx1[q] = cx1[cb0 + q]; ly1[q] = cy1[cb0 + q];
        lx2[q] = cx2[cb0 + q]; ly2[q] = cy2[cb0 + q];
        lar[q] = car[cb0 + q];
    }
    __syncthreads();

    int wv = threadIdx.x >> 6, lane = threadIdx.x & 63;
    int t = tbase + wv;
    if (t >= T) return;
    int w = (int)((sqrtf(8.0f * (float)t + 1.0f) - 1.0f) * 0.5f);
    while (((w + 1) * (w + 2)) / 2 <= t) w++;
    while ((w * (w + 1)) / 2 > t) w--;
    int c = t - ((w * (w + 1)) >> 1);

    size_t mOff = (size_t)img * 68056 + (size_t)lvl * 16000;
    int Wa = (lvl == 4) ? 8 : 16;
    unsigned long long* M = maskBuf + mOff;

    int j = (w << 6) + lane;
    bool jv = j < m;
    float jx1 = jv ? lx1[j] : 0.f, jy1 = jv ? ly1[j] : 0.f;
    float jx2 = jv ? lx2[j] : 0.f, jy2 = jv ? ly2[j] : 0.f;
    float jar = jv ? lar[j] : 0.f;

    unsigned long long myword = 0ULL;
    unsigned long long tcol = 0ULL;  // transposed: bit i = (row i0+i suppresses col j)
    int i0 = c << 6, i1 = min(i0 + 64, m);
    for (int i = i0; i < i1; i++) {
        float ix1 = lx1[i], iy1 = ly1[i], ix2 = lx2[i], iy2 = ly2[i], iar = lar[i];
        float ltx = fmaxf(ix1, jx1);
        float lty = fmaxf(iy1, jy1);
        float rbx = fminf(ix2, jx2);
        float rby = fminf(iy2, jy2);
        float wq = fmaxf(__fsub_rn(rbx, ltx), 0.0f);
        float hq = fmaxf(__fsub_rn(rby, lty), 0.0f);
        float inter = __fmul_rn(wq, hq);
        float uni = __fsub_rn(__fadd_rn(iar, jar), inter);
        float iou = inter / uni;  // keep IEEE div: decisions must match reference exactly
        bool bit = jv && (j > i) && (iou > 0.7f);
        tcol |= (unsigned long long)bit << (i - i0);
        unsigned long long bal = __ballot(bit);
        if (lane == (i & 63)) myword = bal;
    }
    int irow = i0 + lane;
    if (irow < i1) M[(size_t)irow * Wa + w] = myword;
    if (w == c) dtileBuf[((size_t)iq * 16 + w) * 64 + lane] = tcol;
}

// ---------- stage C2: tile-serial greedy scan — register chain + UNROLLED parallel OR ----------

__global__ __launch_bounds__(256, 1) void scan_kernel(
    const unsigned long long* __restrict__ maskBuf,
    const unsigned long long* __restrict__ dtileBuf, const int* __restrict__ cm,
    unsigned long long* __restrict__ keepWords) {
    __shared__ unsigned long long sbuf[2][CHUNK * 16];  // 64 KB double buffer
    int grp = blockIdx.x;
    int img = grp / 5, lvl = grp % 5;
    int m = cm[grp];
    int W = (m + 63) >> 6;
    int Wa = (lvl == 4) ? 8 : 16;
    const unsigned long long* M = maskBuf + (size_t)img * 68056 + (size_t)lvl * 16000;
    const unsigned long long* D = dtileBuf + (size_t)grp * 16 * 64;
    int tid = threadIdx.x;
    int wv = tid >> 6, lane = tid & 63;
    int nch = (m + CHUNK - 1) / CHUNK;

    {
        int words0 = min(CHUNK, m) * Wa;
        for (int u = tid; u < words0; u += 256) sbuf[0][u] = M[u];
    }

    unsigned long long acc = 0ULL;  // wave 0, lane w: removal word w
    unsigned long long dt0 = 0, dt1 = 0, dt2 = 0, dt3 = 0;
    if (wv == 0) {
        if (0 < W) dt0 = D[0 * 64 + lane];
        if (1 < W) dt1 = D[1 * 64 + lane];
        if (2 < W) dt2 = D[2 * 64 + lane];
        if (3 < W) dt3 = D[3 * 64 + lane];
    }
    __syncthreads();

    for (int ch = 0; ch < nch; ch++) {
        if (wv > 0 && ch + 1 < nch) {  // waves 1-3: stage next chunk
            int rbase = (ch + 1) * CHUNK;
            int wordsN = (min(rbase + CHUNK, m) - rbase) * Wa;
            const unsigned long long* srcp = M + (size_t)rbase * Wa;
            unsigned long long* dstp = sbuf[(ch + 1) & 1];
            for (int u = tid - 64; u < wordsN; u += 192) dstp[u] = srcp[u];
        }
        if (wv == 0) {
            unsigned long long nt0 = 0, nt1 = 0, nt2 = 0, nt3 = 0;
            if (ch + 1 < nch) {
                int tb = (ch + 1) * 4;
                if (tb + 0 < W) nt0 = D[(tb + 0) * 64 + lane];
                if (tb + 1 < W) nt1 = D[(tb + 1) * 64 + lane];
                if (tb + 2 < W) nt2 = D[(tb + 2) * 64 + lane];
                if (tb + 3 < W) nt3 = D[(tb + 3) * 64 + lane];
            }
            const unsigned long long* buf = sbuf[ch & 1];
#define TILE(DT, Q)                                                                      \
            {                                                                            \
                int t = ch * 4 + (Q);                                                    \
                if (t < W) {                                                             \
                    int iend = min(64, m - (t << 6));                                    \
                    unsigned long long rw = shfl_u64(acc, t);                            \
                    bool deadbit = ((rw >> lane) & 1ULL) != 0ULL;                        \
                    unsigned long long C = (DT);                                         \
                    _Pragma("unroll")                                                    \
                    for (int i = 0; i < 64; i++) {                                       \
                        unsigned long long bal = __ballot(deadbit);                      \
                        bool alive = ((bal >> i) & 1ULL) == 0ULL;                        \
                        deadbit = deadbit || (alive && (((C >> i) & 1ULL) != 0ULL));     \
                    }                                                                    \
                    unsigned long long A = __ballot(!deadbit);                           \
                    if (lane == 0) keepWords[grp * 16 + t] = A;                          \
                    if (lane < W) {                                                      \
                        const unsigned long long* bp =                                   \
                            buf + ((size_t)((t - ch * 4) << 6)) * Wa + lane;             \
                        unsigned long long a0 = 0, a1 = 0, a2 = 0, a3 = 0;               \
                        if (iend == 64) {                                                \
                            _Pragma("unroll")                                            \
                            for (int i = 0; i < 64; i += 4) {                            \
                                unsigned long long v0 = bp[(size_t)(i + 0) * Wa];        \
                                unsigned long long v1 = bp[(size_t)(i + 1) * Wa];        \
                                unsigned long long v2 = bp[(size_t)(i + 2) * Wa];        \
                                unsigned long long v3 = bp[(size_t)(i + 3) * Wa];        \
                                a0 |= v0 & (0ULL - ((A >> (i + 0)) & 1ULL));             \
                                a1 |= v1 & (0ULL - ((A >> (i + 1)) & 1ULL));             \
                                a2 |= v2 & (0ULL - ((A >> (i + 2)) & 1ULL));             \
                                a3 |= v3 & (0ULL - ((A >> (i + 3)) & 1ULL));             \
                            }                                                            \
                        } else {                                                         \
                            for (int i = 0; i < iend; i++) {                             \
                                unsigned long long v = bp[(size_t)i * Wa];               \
                                a0 |= v & (0ULL - ((A >> i) & 1ULL));                    \
                            }                                                            \
                        }                                                                \
                        acc |= (a0 | a1) | (a2 | a3);                                    \
                    }                                                                    \
                }                                                                        \
            }
            TILE(dt0, 0) TILE(dt1, 1) TILE(dt2, 2) TILE(dt3, 3)
#undef TILE
            dt0 = nt0; dt1 = nt1; dt2 = nt2; dt3 = nt3;
        }
        __syncthreads();
    }
}

// ---------- stage D: compaction + global rank + output ----------

__global__ __launch_bounds__(1024) void scanout_kernel(
    const float* __restrict__ sx1, const float* __restrict__ sy1,
    const float* __restrict__ sx2, const float* __restrict__ sy2,
    const float* __restrict__ sscore,
    const unsigned long long* __restrict__ ckey, const int* __restrict__ cslot,
    const int* __restrict__ cm, const unsigned long long* __restrict__ keepWords,
    float* __restrict__ out) {
    __shared__ unsigned long long kkey[SLOTCAP];
    __shared__ int kslot[SLOTCAP];
    __shared__ int s_warp[32];
    __shared__ int s_cnt[5];

    int img = blockIdx.x, tid = threadIdx.x;

    for (int lvl = 0; lvl < 5; lvl++) {
        int m = cm[img * 5 + lvl];
        int koff = lvl * 1000;
        int flag = 0;
        if (tid < m)
            flag = (int)((keepWords[(img * 5 + lvl) * 16 + (tid >> 6)] >> (tid & 63)) & 1ULL);
        int pos = blockExclScan(flag, s_warp);
        if (flag) {
            size_t cb = (size_t)img * SLOTCAP + koff + tid;
            kkey[koff + pos] = ckey[cb];
            kslot[koff + pos] = cslot[cb];
        }
        if (tid == 1023) s_cnt[lvl] = pos + flag;
        __syncthreads();
    }

    int tK = s_cnt[0] + s_cnt[1] + s_cnt[2] + s_cnt[3] + s_cnt[4];

    for (int lvl = 0; lvl < 5; lvl++) {
        int Kc = s_cnt[lvl];
        int koff = lvl * 1000;
        for (int q = tid; q < Kc; q += 1024) {
            unsigned long long key = kkey[koff + q];
            int rank = q;
#pragma unroll
            for (int ol = 0; ol < 5; ol++) {
                if (ol == lvl) continue;
                int lo = 0, hi = s_cnt[ol], base = ol * 1000;
                while (lo < hi) {
                    int mid = (lo + hi) >> 1;
                    if (kkey[base + mid] > key) lo = mid + 1; else hi = mid;
                }
                rank += lo;
            }
            if (rank < POSTN) {
                int slot = kslot[koff + q];
                size_t o = (size_t)img * KTOT + slot;
                float* dst = out + ((size_t)img * POSTN + rank) * 5;
                dst[0] = sx1[o]; dst[1] = sy1[o]; dst[2] = sx2[o]; dst[3] = sy2[o];
                dst[4] = sscore[o];
            }
        }
    }

    int z0 = tK < POSTN ? tK : POSTN;
    int nz = (POSTN - z0) * 5;
    float* ob = out + (size_t)img * POSTN * 5 + (size_t)z0 * 5;
    for (int u = tid; u < nz; u += 1024) ob[u] = 0.f;
}

// ---------- host ----------

extern "C" void kernel_launch(void* const* d_in, const int* in_sizes, int n_in,
                              void* d_out, int out_size, void* d_ws, size_t ws_size,
                              hipStream_t stream) {
    const float* obj = (const float*)d_in[0];
    const float* deltas = (const float*)d_in[1];
    const float* anchors = (const float*)d_in[2];
    float* out = (float*)d_out;

    char* ws = (char*)d_ws;
    size_t off = 0;
    auto alloc = [&](size_t bytes) {
        size_t o = off;
        off += (bytes + 255) & ~(size_t)255;
        return o;
    };
    unsigned* ghist = (unsigned*)(ws + alloc((size_t)NIMG * 5 * 4096 * 4));
    int* gcnt = (int*)(ws + alloc((size_t)NIMG * BPI * 4));
    unsigned long long* gcand =
        (unsigned long long*)(ws + alloc((size_t)NIMG * BPI * CAND_CAP * 8));
    float* sx1 = (float*)(ws + alloc((size_t)NIMG * KTOT * 4));
    float* sy1 = (float*)(ws + alloc((size_t)NIMG * KTOT * 4));
    float* sx2 = (float*)(ws + alloc((size_t)NIMG * KTOT * 4));
    float* sy2 = (float*)(ws + alloc((size_t)NIMG * KTOT * 4));
    float* sscore = (float*)(ws + alloc((size_t)NIMG * KTOT * 4));
    float* cx1 = (float*)(ws + alloc((size_t)NIMG * SLOTCAP * 4));
    float* cy1 = (float*)(ws + alloc((size_t)NIMG * SLOTCAP * 4));
    float* cx2 = (float*)(ws + alloc((size_t)NIMG * SLOTCAP * 4));
    float* cy2 = (float*)(ws + alloc((size_t)NIMG * SLOTCAP * 4));
    float* car = (float*)(ws + alloc((size_t)NIMG * SLOTCAP * 4));
    unsigned long long* ckey = (unsigned long long*)(ws + alloc((size_t)NIMG * SLOTCAP * 8));
    int* cslot = (int*)(ws + alloc((size_t)NIMG * SLOTCAP * 4));
    int* cm = (int*)(ws + alloc((size_t)NIMG * 5 * 4));
    unsigned long long* maskBuf = (unsigned long long*)(ws + alloc((size_t)NIMG * 68056ULL * 8));
    unsigned long long* dtileBuf =
        (unsigned long long*)(ws + alloc((size_t)NIMG * 5 * 16 * 64 * 8));
    unsigned long long* keepWords = (unsigned long long*)(ws + alloc((size_t)NIMG * 5 * 16 * 8));

    hipMemsetAsync(ghist, 0, (size_t)NIMG * 5 * 4096 * 4, stream);

    hist_kernel<<<dim3(NIMG * BPI), dim3(1024), 0, stream>>>(obj, ghist);
    gather_kernel<<<dim3(NIMG * BPI), dim3(1024), 0, stream>>>(obj, ghist, gcand, gcnt);
    rankdecode_kernel<<<dim3(NIMG * 5), dim3(1024), 0, stream>>>(
        deltas, anchors, gcand, gcnt, sx1, sy1, sx2, sy2, sscore,
        cx1, cy1, cx2, cy2, car, ckey, cslot, cm);
    mask_kernel<<<dim3(17, NIMG * 5), dim3(512), 0, stream>>>(cx1, cy1, cx2, cy2, car, cm,
                                                              maskBuf, dtileBuf);
    scan_kernel<<<dim3(NIMG * 5), dim3(256), 0, stream>>>(maskBuf, dtileBuf, cm, keepWords);
    scanout_kernel<<<dim3(NIMG), dim3(1024), 0, stream>>>(
        sx1, sy1, sx2, sy2, sscore, ckey, cslot, cm, keepWords, out);
}

// Round 10
// 209.841 us; speedup vs baseline: 1.7861x; 1.0703x over previous
//
#include <hip/hip_runtime.h>
#include <stdint.h>

#define KTOT 4507
#define POSTN 1000
#define ATOT 159882
#define NIMG 4
#define CAND_CAP 4096
#define SLOTCAP 5000  // per-image compact capacity (koff spacing = lvl*1000)
#define BPI 22        // hist/gather blocks per image: 15+4+1+1+1
#define MT_IMG 69632  // per-image transposed-mask words: 4*16*1024 + 8*512

// ---------- helpers ----------

__device__ inline unsigned fmono(float f) {
    unsigned u = __float_as_uint(f);
    return (u & 0x80000000u) ? ~u : (u | 0x80000000u);
}
__device__ inline float fmono_inv(unsigned u) {
    unsigned b = (u & 0x80000000u) ? (u ^ 0x80000000u) : ~u;
    return __uint_as_float(b);
}

__device__ inline unsigned long long shfl_u64(unsigned long long v, int src) {
    int lo = __shfl((int)(unsigned)(v & 0xFFFFFFFFULL), src);
    int hi = __shfl((int)(unsigned)(v >> 32), src);
    return ((unsigned long long)(unsigned)hi << 32) | (unsigned)lo;
}

// exclusive prefix over a 1024-thread block; warpSums = LDS int[>=16]; call uniformly.
__device__ inline int blockExclScan(int v, int* warpSums) {
    int tid = threadIdx.x;
    int lane = tid & 63, wid = tid >> 6;
    int x = v;
#pragma unroll
    for (int d = 1; d < 64; d <<= 1) {
        int y = __shfl_up(x, d);
        if (lane >= d) x += y;
    }
    if (lane == 63) warpSums[wid] = x;
    __syncthreads();
    if (wid == 0) {
        int s = (lane < 16) ? warpSums[lane] : 0;
#pragma unroll
        for (int d = 1; d < 16; d <<= 1) {
            int y = __shfl_up(s, d);
            if (lane >= d) s += y;
        }
        if (lane < 16) warpSums[lane] = s;
    }
    __syncthreads();
    int wpre = (wid == 0) ? 0 : warpSums[wid - 1];
    return wpre + (x - v);
}

__device__ __constant__ int c_lvlOff[5] = {0, 120000, 150000, 157500, 159375};
__device__ __constant__ int c_lvlN[5]   = {120000, 30000, 7500, 1875, 507};
__device__ __constant__ int c_slsz[5]   = {8000, 7500, 7500, 1875, 507};
__device__ __constant__ int c_blvl[BPI] = {0,0,0,0,0,0,0,0,0,0,0,0,0,0,0, 1,1,1,1, 2, 3, 4};
__device__ __constant__ int c_bsl[BPI]  = {0,1,2,3,4,5,6,7,8,9,10,11,12,13,14, 0,1,2,3, 0, 0, 0};
__device__ __constant__ int c_bstart[5] = {0, 15, 19, 20, 21};
__device__ __constant__ int c_bcnt[5]   = {15, 4, 1, 1, 1};

// transposed mask geometry: lvl<4 -> 16 word-cols x 1024 rows; lvl4 -> 8 x 512
__device__ inline size_t mtBase(int img, int lvl) {
    return (size_t)img * MT_IMG + (lvl < 4 ? (size_t)lvl * 16384 : 65536);
}

// ---------- stage A1: sliced histogram -> global per-(img,lvl) 4096-bin hist ----------

__global__ __launch_bounds__(1024) void hist_kernel(const float* __restrict__ obj,
                                                    unsigned* __restrict__ ghist) {
    __shared__ unsigned hist[4096];
    int img = blockIdx.x / BPI, b = blockIdx.x % BPI;
    int lvl = c_blvl[b], sl = c_bsl[b];
    int n = c_lvlN[lvl];
    int s0 = sl * c_slsz[lvl];
    int send = min(s0 + c_slsz[lvl], n);
    const float* src = obj + (size_t)img * ATOT + c_lvlOff[lvl];
    int tid = threadIdx.x;

    for (int i = tid; i < 4096; i += 1024) hist[i] = 0u;
    __syncthreads();

    int base = s0 + tid, last = send - 1;
    float v0 = src[min(base,        last)];
    float v1 = src[min(base + 1024, last)];
    float v2 = src[min(base + 2048, last)];
    float v3 = src[min(base + 3072, last)];
    float v4 = src[min(base + 4096, last)];
    float v5 = src[min(base + 5120, last)];
    float v6 = src[min(base + 6144, last)];
    float v7 = src[min(base + 7168, last)];
#define HIST1(U, VV) if (base + (U)*1024 < send) atomicAdd(&hist[fmono(VV) >> 20], 1u);
    HIST1(0, v0) HIST1(1, v1) HIST1(2, v2) HIST1(3, v3)
    HIST1(4, v4) HIST1(5, v5) HIST1(6, v6) HIST1(7, v7)
#undef HIST1
    __syncthreads();

    unsigned* gh = ghist + (size_t)(img * 5 + lvl) * 4096;
    for (int i = tid; i < 4096; i += 1024) {
        unsigned c = hist[i];
        if (c) atomicAdd(&gh[i], c);
    }
}

// ---------- stage A2: per-slice gather into PRIVATE segment (LDS counter only) ----------

__global__ __launch_bounds__(1024) void gather_kernel(const float* __restrict__ obj,
                                                      const unsigned* __restrict__ ghist,
                                                      unsigned long long* __restrict__ gcand,
                                                      int* __restrict__ gcnt) {
    __shared__ int s_misc[32];
    __shared__ int s_bstar, s_cnt;
    int img = blockIdx.x / BPI, b = blockIdx.x % BPI;
    int lvl = c_blvl[b], sl = c_bsl[b];
    int grp = img * 5 + lvl;
    int seg = img * BPI + b;
    int n = c_lvlN[lvl];
    int k = (lvl == 4) ? 507 : 1000;
    int s0 = sl * c_slsz[lvl];
    int send = min(s0 + c_slsz[lvl], n);
    const float* src = obj + (size_t)img * ATOT + c_lvlOff[lvl];
    int tid = threadIdx.x;
    int lane = tid & 63;

    if (tid == 0) s_cnt = 0;

    const uint4* gh4 = (const uint4*)(ghist + (size_t)grp * 4096);
    uint4 cc = gh4[tid];
    int mysum = (int)(cc.x + cc.y + cc.z + cc.w);
    int excl = blockExclScan(mysum, s_misc);
    int target = n - k;
    {
        int P = excl;
        if ((int)cc.x > 0 && P <= target && target < P + (int)cc.x) s_bstar = 4 * tid + 0;
        P += (int)cc.x;
        if ((int)cc.y > 0 && P <= target && target < P + (int)cc.y) s_bstar = 4 * tid + 1;
        P += (int)cc.y;
        if ((int)cc.z > 0 && P <= target && target < P + (int)cc.z) s_bstar = 4 * tid + 2;
        P += (int)cc.z;
        if ((int)cc.w > 0 && P <= target && target < P + (int)cc.w) s_bstar = 4 * tid + 3;
    }
    __syncthreads();
    int bstar = s_bstar;

    unsigned long long* gc = gcand + (size_t)seg * CAND_CAP;
    int base = s0 + tid, last = send - 1;
    float v0 = src[min(base,        last)];
    float v1 = src[min(base + 1024, last)];
    float v2 = src[min(base + 2048, last)];
    float v3 = src[min(base + 3072, last)];
    float v4 = src[min(base + 4096, last)];
    float v5 = src[min(base + 5120, last)];
    float v6 = src[min(base + 6144, last)];
    float v7 = src[min(base + 7168, last)];
#define PUSH1(U, VV)                                                                     \
    {                                                                                    \
        int ix = base + (U) * 1024;                                                      \
        unsigned key = fmono(VV);                                                        \
        bool s = (ix < send) && ((int)(key >> 20) >= bstar);                             \
        unsigned long long mk = __ballot(s);                                             \
        if (mk) {                                                                        \
            int pre = __popcll(mk & ((1ULL << lane) - 1ULL));                            \
            int ldr = __builtin_ctzll(mk);                                               \
            int basew = 0;                                                               \
            if (lane == ldr) basew = atomicAdd(&s_cnt, __popcll(mk));                    \
            basew = __shfl(basew, ldr);                                                  \
            if (s) {                                                                     \
                int pos = basew + pre;                                                   \
                if (pos < CAND_CAP)                                                      \
                    gc[pos] = ((unsigned long long)key << 32) | (unsigned)(~(unsigned)ix); \
            }                                                                            \
        }                                                                                \
    }
    PUSH1(0, v0) PUSH1(1, v1) PUSH1(2, v2) PUSH1(3, v3)
    PUSH1(4, v4) PUSH1(5, v5) PUSH1(6, v6) PUSH1(7, v7)
#undef PUSH1
    __syncthreads();
    if (tid == 0) gcnt[seg] = min(s_cnt, CAND_CAP);
}

// ---------- stage B: concat segments + bitonic sort + decode + compaction (fused) ----------

__global__ __launch_bounds__(1024) void rankdecode_kernel(
    const float* __restrict__ deltas, const float* __restrict__ anchors,
    const unsigned long long* __restrict__ gcand, const int* __restrict__ gcnt,
    float* __restrict__ sx1, float* __restrict__ sy1, float* __restrict__ sx2,
    float* __restrict__ sy2, float* __restrict__ sscore,
    float* __restrict__ cx1, float* __restrict__ cy1, float* __restrict__ cx2,
    float* __restrict__ cy2, float* __restrict__ car,
    unsigned long long* __restrict__ ckey, int* __restrict__ cslot, int* __restrict__ cm) {
    __shared__ unsigned long long ck[CAND_CAP];
    __shared__ int s_warp[32];

    int grp = blockIdx.x;
    int img = grp / 5, lvl = grp % 5;
    int kn = (lvl == 4) ? 507 : 1000;
    int koff = lvl * 1000;
    int tid = threadIdx.x;

    int bs = c_bstart[lvl], bc = c_bcnt[lvl];
    int pref = 0;
    for (int s = 0; s < bc; s++) {
        int c = gcnt[img * BPI + bs + s];
        const unsigned long long* segp = gcand + (size_t)(img * BPI + bs + s) * CAND_CAP;
        for (int i = tid; i < c; i += 1024) {
            int d = pref + i;
            if (d < CAND_CAP) ck[d] = segp[i];
        }
        pref += c;
    }
    int m = min(pref, CAND_CAP);
    int P = 512;
    while (P < m) P <<= 1;
    for (int i = m + tid; i < P; i += 1024) ck[i] = 0ULL;
    __syncthreads();

    for (unsigned kk = 2; kk <= (unsigned)P; kk <<= 1) {
        for (unsigned j = kk >> 1; j > 0; j >>= 1) {
            for (unsigned i = (unsigned)tid; i < (unsigned)P; i += 1024) {
                unsigned ixj = i ^ j;
                if (ixj > i) {
                    unsigned long long a = ck[i], b = ck[ixj];
                    bool up = ((i & kk) == 0);
                    if ((a > b) == up) { ck[i] = b; ck[ixj] = a; }
                }
            }
            __syncthreads();
        }
    }

    int r = tid;
    size_t o = (size_t)img * KTOT + koff + r;
    float x1 = 0.f, y1 = 0.f, x2 = 0.f, y2 = 0.f, s = 0.f;
    int valid = 0;
    if (r < kn) {
        unsigned long long key = ck[P - 1 - r];
        int idx = c_lvlOff[lvl] + (int)(~(unsigned)key);
        float logit = fmono_inv((unsigned)(key >> 32));
        float ef = (float)exp(-(double)logit);
        s = 1.0f / __fadd_rn(1.0f, ef);
        float a0 = anchors[(size_t)idx * 4 + 0], a1 = anchors[(size_t)idx * 4 + 1];
        float a2 = anchors[(size_t)idx * 4 + 2], a3 = anchors[(size_t)idx * 4 + 3];
        const float* dp = deltas + ((size_t)img * ATOT + idx) * 4;
        float dx = dp[0], dy = dp[1];
        const float BCLIP = 4.135166556742356f;  // log(1000/16)
        float dw = fminf(dp[2], BCLIP), dh = fminf(dp[3], BCLIP);
        float wa = __fsub_rn(a2, a0), ha = __fsub_rn(a3, a1);
        float cxa = __fadd_rn(a0, __fmul_rn(0.5f, wa));
        float cya = __fadd_rn(a1, __fmul_rn(0.5f, ha));
        float cx = __fadd_rn(__fmul_rn(dx, wa), cxa);
        float cy = __fadd_rn(__fmul_rn(dy, ha), cya);
        float w = __fmul_rn((float)exp((double)dw), wa);
        float h = __fmul_rn((float)exp((double)dh), ha);
        x1 = __fsub_rn(cx, __fmul_rn(0.5f, w));
        y1 = __fsub_rn(cy, __fmul_rn(0.5f, h));
        x2 = __fadd_rn(cx, __fmul_rn(0.5f, w));
        y2 = __fadd_rn(cy, __fmul_rn(0.5f, h));
        x1 = fminf(fmaxf(x1, 0.0f), 800.0f);
        y1 = fminf(fmaxf(y1, 0.0f), 800.0f);
        x2 = fminf(fmaxf(x2, 0.0f), 800.0f);
        y2 = fminf(fmaxf(y2, 0.0f), 800.0f);
        valid = (__fsub_rn(x2, x1) >= 0.001f) && (__fsub_rn(y2, y1) >= 0.001f) && (s >= 0.0f);
        sx1[o] = x1; sy1[o] = y1; sx2[o] = x2; sy2[o] = y2; sscore[o] = s;
    }

    int pos = blockExclScan(valid, s_warp);
    if (valid) {
        float lf = 1000.0f * (float)lvl;
        size_t cb = (size_t)img * SLOTCAP + koff + pos;
        float ox1 = __fadd_rn(x1, lf);
        float oy1 = __fadd_rn(y1, lf);
        float ox2 = __fadd_rn(x2, lf);
        float oy2 = __fadd_rn(y2, lf);
        cx1[cb] = ox1; cy1[cb] = oy1; cx2[cb] = ox2; cy2[cb] = oy2;
        car[cb] = __fmul_rn(__fsub_rn(ox2, ox1), __fsub_rn(oy2, oy1));
        int p = koff + r;
        ckey[cb] = ((unsigned long long)fmono(s) << 32) | (unsigned)(~(unsigned)p);
        cslot[cb] = p;
    }
    if (tid == 1023) cm[grp] = pos + valid;
}

// ---------- stage C: mask build (TRANSPOSED word-major layout + diagonal tiles) ----------

__global__ __launch_bounds__(512) void mask_kernel(
    const float* __restrict__ cx1, const float* __restrict__ cy1,
    const float* __restrict__ cx2, const float* __restrict__ cy2,
    const float* __restrict__ car, const int* __restrict__ cm,
    unsigned long long* __restrict__ maskT, unsigned long long* __restrict__ dtileBuf) {
    __shared__ float lx1[1000], ly1[1000], lx2[1000], ly2[1000], lar[1000];
    int iq = blockIdx.y;
    int img = iq / 5, lvl = iq % 5;
    int m = cm[iq];
    int W = (m + 63) >> 6;
    int T = (W * (W + 1)) >> 1;
    int tbase = blockIdx.x * 8;
    if (tbase >= T) return;

    size_t cb0 = (size_t)img * SLOTCAP + lvl * 1000;
    for (int q = threadIdx.x; q < m; q += 512) {
        lx1[q] = cx1[cb0 + q]; ly1[q] = cy1[cb0 + q];
        lx2[q] = cx2[cb0 + q]; ly2[q] = cy2[cb0 + q];
        lar[q] = car[cb0 + q];
    }
    __syncthreads();

    int wv = threadIdx.x >> 6, lane = threadIdx.x & 63;
    int t = tbase + wv;
    if (t >= T) return;
    int w = (int)((sqrtf(8.0f * (float)t + 1.0f) - 1.0f) * 0.5f);
    while (((w + 1) * (w + 2)) / 2 <= t) w++;
    while ((w * (w + 1)) / 2 > t) w--;
    int c = t - ((w * (w + 1)) >> 1);

    int rA = (lvl == 4) ? 512 : 1024;
    unsigned long long* MT = maskT + mtBase(img, lvl);

    int j = (w << 6) + lane;
    bool jv = j < m;
    float jx1 = jv ? lx1[j] : 0.f, jy1 = jv ? ly1[j] : 0.f;
    float jx2 = jv ? lx2[j] : 0.f, jy2 = jv ? ly2[j] : 0.f;
    float jar = jv ? lar[j] : 0.f;

    unsigned long long myword = 0ULL;
    unsigned long long tcol = 0ULL;  // transposed: bit i = (row i0+i suppresses col j)
    int i0 = c << 6, i1 = min(i0 + 64, m);
    for (int i = i0; i < i1; i++) {
        float ix1 = lx1[i], iy1 = ly1[i], ix2 = lx2[i], iy2 = ly2[i], iar = lar[i];
        float ltx = fmaxf(ix1, jx1);
        float lty = fmaxf(iy1, jy1);
        float rbx = fminf(ix2, jx2);
        float rby = fminf(iy2, jy2);
        float wq = fmaxf(__fsub_rn(rbx, ltx), 0.0f);
        float hq = fmaxf(__fsub_rn(rby, lty), 0.0f);
        float inter = __fmul_rn(wq, hq);
        float uni = __fsub_rn(__fadd_rn(iar, jar), inter);
        float iou = inter / uni;  // keep IEEE div: decisions must match reference exactly
        bool bit = jv && (j > i) && (iou > 0.7f);
        tcol |= (unsigned long long)bit << (i - i0);
        unsigned long long bal = __ballot(bit);
        if (lane == (i & 63)) myword = bal;
    }
    int irow = i0 + lane;
    if (irow < i1) MT[(size_t)w * rA + irow] = myword;  // coalesced across lanes
    if (w == c) dtileBuf[((size_t)iq * 16 + w) * 64 + lane] = tcol;
}

// ---------- stage C2: single-wave tile-serial greedy scan, no LDS, no barriers ----------
// lane = g*16 + w16: handles word-column w16, row sub-range g*16..g*16+15 of each tile.
// Per tile: 8 independent 16B loads issued BEFORE the register-only ballot chain
// (latency hidden), OR under keep-mask, 2-shfl reduce. Zero memory ops in the chain.

__global__ __launch_bounds__(64, 1) void scan_kernel(
    const unsigned long long* __restrict__ maskT,
    const unsigned long long* __restrict__ dtileBuf, const int* __restrict__ cm,
    unsigned long long* __restrict__ keepWords) {
    int grp = blockIdx.x;
    int img = grp / 5, lvl = grp % 5;
    int m = cm[grp];
    int W = (m + 63) >> 6;
    int rA = (lvl == 4) ? 512 : 1024;
    const unsigned long long* MT = maskT + mtBase(img, lvl);
    const unsigned long long* D = dtileBuf + (size_t)grp * 16 * 64;
    int lane = threadIdx.x;
    int w16 = lane & 15, g = lane >> 4;
    const unsigned long long* Mw = MT + (size_t)w16 * rA;
    unsigned long long ownmask = (w16 < W) ? ~0ULL : 0ULL;
    unsigned long long acc = 0ULL;  // lanes 0..15: removal word w16
    unsigned long long dtC = (0 < W) ? D[lane] : 0ULL;

    for (int t = 0; t < W; t++) {
        // issue this tile's 8x16B row-word loads (independent of the chain)
        const ulonglong2* vp = (const ulonglong2*)(Mw + (size_t)((t << 6) + (g << 4)));
        ulonglong2 v0 = vp[0], v1 = vp[1], v2 = vp[2], v3 = vp[3];
        ulonglong2 v4 = vp[4], v5 = vp[5], v6 = vp[6], v7 = vp[7];
        // prefetch next tile's diagonal
        unsigned long long dtN = (t + 1 < W) ? D[((t + 1) << 6) + lane] : 0ULL;

        // within-tile greedy chain (register-only; identical decisions to prior rounds)
        unsigned long long rw = shfl_u64(acc, t);
        bool deadbit = ((rw >> lane) & 1ULL) != 0ULL;
        unsigned long long C = dtC;
#pragma unroll
        for (int i = 0; i < 64; i++) {
            unsigned long long bal = __ballot(deadbit);
            bool alive = ((bal >> i) & 1ULL) == 0ULL;
            deadbit = deadbit || (alive && (((C >> i) & 1ULL) != 0ULL));
        }
        unsigned long long A = __ballot(!deadbit);
        if (lane == 0) keepWords[grp * 16 + t] = A;

        int iend = min(64, m - (t << 6));
        unsigned long long At = (iend == 64) ? A : (A & ((1ULL << iend) - 1ULL));
        unsigned long long Ag = At >> (g << 4);  // the 16 keep bits this lane handles
        unsigned long long p = 0ULL;
#define ORV(VV, I0)                                                                      \
        p |= VV.x & (0ULL - ((Ag >> (I0)) & 1ULL));                                      \
        p |= VV.y & (0ULL - ((Ag >> ((I0) + 1)) & 1ULL));
        ORV(v0, 0)  ORV(v1, 2)  ORV(v2, 4)  ORV(v3, 6)
        ORV(v4, 8)  ORV(v5, 10) ORV(v6, 12) ORV(v7, 14)
#undef ORV
        p &= ownmask;
        // reduce the 4 row-subrange partials onto lanes 0..15
        p |= shfl_u64(p, (lane + 32) & 63);
        p |= shfl_u64(p, (lane + 16) & 63);
        acc |= p;
        dtC = dtN;
    }
}

// ---------- stage D: compaction + global rank + output ----------

__global__ __launch_bounds__(1024) void scanout_kernel(
    const float* __restrict__ sx1, const float* __restrict__ sy1,
    const float* __restrict__ sx2, const float* __restrict__ sy2,
    const float* __restrict__ sscore,
    const unsigned long long* __restrict__ ckey, const int* __restrict__ cslot,
    const int* __restrict__ cm, const unsigned long long* __restrict__ keepWords,
    float* __restrict__ out) {
    __shared__ unsigned long long kkey[SLOTCAP];
    __shared__ int kslot[SLOTCAP];
    __shared__ int s_warp[32];
    __shared__ int s_cnt[5];

    int img = blockIdx.x, tid = threadIdx.x;

    for (int lvl = 0; lvl < 5; lvl++) {
        int m = cm[img * 5 + lvl];
        int koff = lvl * 1000;
        int flag = 0;
        if (tid < m)
            flag = (int)((keepWords[(img * 5 + lvl) * 16 + (tid >> 6)] >> (tid & 63)) & 1ULL);
        int pos = blockExclScan(flag, s_warp);
        if (flag) {
            size_t cb = (size_t)img * SLOTCAP + koff + tid;
            kkey[koff + pos] = ckey[cb];
            kslot[koff + pos] = cslot[cb];
        }
        if (tid == 1023) s_cnt[lvl] = pos + flag;
        __syncthreads();
    }

    int tK = s_cnt[0] + s_cnt[1] + s_cnt[2] + s_cnt[3] + s_cnt[4];

    for (int lvl = 0; lvl < 5; lvl++) {
        int Kc = s_cnt[lvl];
        int koff = lvl * 1000;
        for (int q = tid; q < Kc; q += 1024) {
            unsigned long long key = kkey[koff + q];
            int rank = q;
#pragma unroll
            for (int ol = 0; ol < 5; ol++) {
                if (ol == lvl) continue;
                int lo = 0, hi = s_cnt[ol], base = ol * 1000;
                while (lo < hi) {
                    int mid = (lo + hi) >> 1;
                    if (kkey[base + mid] > key) lo = mid + 1; else hi = mid;
                }
                rank += lo;
            }
            if (rank < POSTN) {
                int slot = kslot[koff + q];
                size_t o = (size_t)img * KTOT + slot;
                float* dst = out + ((size_t)img * POSTN + rank) * 5;
                dst[0] = sx1[o]; dst[1] = sy1[o]; dst[2] = sx2[o]; dst[3] = sy2[o];
                dst[4] = sscore[o];
            }
        }
    }

    int z0 = tK < POSTN ? tK : POSTN;
    int nz = (POSTN - z0) * 5;
    float* ob = out + (size_t)img * POSTN * 5 + (size_t)z0 * 5;
    for (int u = tid; u < nz; u += 1024) ob[u] = 0.f;
}

// ---------- host ----------

extern "C" void kernel_launch(void* const* d_in, const int* in_sizes, int n_in,
                              void* d_out, int out_size, void* d_ws, size_t ws_size,
                              hipStream_t stream) {
    const float* obj = (const float*)d_in[0];
    const float* deltas = (const float*)d_in[1];
    const float* anchors = (const float*)d_in[2];
    float* out = (float*)d_out;

    char* ws = (char*)d_ws;
    size_t off = 0;
    auto alloc = [&](size_t bytes) {
        size_t o = off;
        off += (bytes + 255) & ~(size_t)255;
        return o;
    };
    unsigned* ghist = (unsigned*)(ws + alloc((size_t)NIMG * 5 * 4096 * 4));
    int* gcnt = (int*)(ws + alloc((size_t)NIMG * BPI * 4));
    unsigned long long* gcand =
        (unsigned long long*)(ws + alloc((size_t)NIMG * BPI * CAND_CAP * 8));
    float* sx1 = (float*)(ws + alloc((size_t)NIMG * KTOT * 4));
    float* sy1 = (float*)(ws + alloc((size_t)NIMG * KTOT * 4));
    float* sx2 = (float*)(ws + alloc((size_t)NIMG * KTOT * 4));
    float* sy2 = (float*)(ws + alloc((size_t)NIMG * KTOT * 4));
    float* sscore = (float*)(ws + alloc((size_t)NIMG * KTOT * 4));
    float* cx1 = (float*)(ws + alloc((size_t)NIMG * SLOTCAP * 4));
    float* cy1 = (float*)(ws + alloc((size_t)NIMG * SLOTCAP * 4));
    float* cx2 = (float*)(ws + alloc((size_t)NIMG * SLOTCAP * 4));
    float* cy2 = (float*)(ws + alloc((size_t)NIMG * SLOTCAP * 4));
    float* car = (float*)(ws + alloc((size_t)NIMG * SLOTCAP * 4));
    unsigned long long* ckey = (unsigned long long*)(ws + alloc((size_t)NIMG * SLOTCAP * 8));
    int* cslot = (int*)(ws + alloc((size_t)NIMG * SLOTCAP * 4));
    int* cm = (int*)(ws + alloc((size_t)NIMG * 5 * 4));
    unsigned long long* maskT = (unsigned long long*)(ws + alloc((size_t)NIMG * MT_IMG * 8));
    unsigned long long* dtileBuf =
        (unsigned long long*)(ws + alloc((size_t)NIMG * 5 * 16 * 64 * 8));
    unsigned long long* keepWords = (unsigned long long*)(ws + alloc((size_t)NIMG * 5 * 16 * 8));

    hipMemsetAsync(ghist, 0, (size_t)NIMG * 5 * 4096 * 4, stream);

    hist_kernel<<<dim3(NIMG * BPI), dim3(1024), 0, stream>>>(obj, ghist);
    gather_kernel<<<dim3(NIMG * BPI), dim3(1024), 0, stream>>>(obj, ghist, gcand, gcnt);
    rankdecode_kernel<<<dim3(NIMG * 5), dim3(1024), 0, stream>>>(
        deltas, anchors, gcand, gcnt, sx1, sy1, sx2, sy2, sscore,
        cx1, cy1, cx2, cy2, car, ckey, cslot, cm);
    mask_kernel<<<dim3(17, NIMG * 5), dim3(512), 0, stream>>>(cx1, cy1, cx2, cy2, car, cm,
                                                              maskT, dtileBuf);
    scan_kernel<<<dim3(NIMG * 5), dim3(64), 0, stream>>>(maskT, dtileBuf, cm, keepWords);
    scanout_kernel<<<dim3(NIMG), dim3(1024), 0, stream>>>(
        sx1, sy1, sx2, sy2, sscore, ckey, cslot, cm, keepWords, out);
}